// Round 1
// baseline (1443.303 us; speedup 1.0000x reference)
//
#include <hip/hip_runtime.h>
#include <hip/hip_bf16.h>
#include <math.h>

#define B_ 4
#define S_ 512
#define H_ 768
#define NH_ 12
#define E_ 24
#define TE_ 20
#define TD_ 20
#define R_ 97
#define DIN_ 1576   // 2*H + TE + TD
#define P_ 552      // E*(E-1)
#define L_ 2208     // B*P
#define NB_ 12      // H/64

// ---------------------------------------------------------------------------
// K1: per-entity gathered attention-row sum over heads + entity features.
// Only the 2*E gathered rows of att are ever needed -> skip full head-sum.
// ---------------------------------------------------------------------------
__global__ void ent_prep(const float* __restrict__ attn, const float* __restrict__ hs,
                         const int* __restrict__ head, const int* __restrict__ tail,
                         float* __restrict__ ent_att, float* __restrict__ ent_feat) {
  int be = blockIdx.x;          // b*E + e
  int b = be / E_;
  int hd = head[be], tl = tail[be];
  int tid = threadIdx.x;
  const float* abase = attn + (size_t)b * NH_ * S_ * S_;
  for (int s = tid; s < S_; s += 256) {
    float acc = 0.f;
#pragma unroll
    for (int nh = 0; nh < NH_; ++nh) {
      const float* ap = abase + (size_t)nh * S_ * S_;
      acc += ap[(size_t)hd * S_ + s] + ap[(size_t)tl * S_ + s];
    }
    ent_att[(size_t)be * S_ + s] = 0.5f * acc;
  }
  const float* hb = hs + (size_t)b * S_ * H_;
  for (int k = tid; k < H_; k += 256) {
    ent_feat[(size_t)be * H_ + k] = 0.5f * (hb[(size_t)hd * H_ + k] + hb[(size_t)tl * H_ + k]);
  }
}

// ---------------------------------------------------------------------------
// K2: pairwise attention product + masking + normalization; pair metadata.
// meta layout [5][L]: 0 feat-row(h), 1 feat-row(t), 2 type-row(h),
//                     3 type-row(t), 4 dist-bucket
// ---------------------------------------------------------------------------
__global__ void pair_att(const float* __restrict__ ent_att, const float* __restrict__ mask,
                         const int* __restrict__ head, const int* __restrict__ tail,
                         const int* __restrict__ etype,
                         float* __restrict__ ht_att, int* __restrict__ meta) {
  int l = blockIdx.x;
  int b = l / P_, p = l % P_;
  int i0 = p / (E_ - 1), rem = p % (E_ - 1);
  int i1 = rem + (rem >= i0 ? 1 : 0);
  int tid = threadIdx.x;
  if (tid == 0) {
    meta[0 * L_ + l] = b * E_ + i0;
    meta[1 * L_ + l] = b * E_ + i1;
    meta[2 * L_ + l] = etype[b * E_ + i0];
    meta[3 * L_ + l] = etype[b * E_ + i1];
    int d = abs(tail[b * E_ + i0] - head[b * E_ + i1]);
    int bk = (d >= 2) + (d >= 4) + (d >= 8) + (d >= 16) + (d >= 32) +
             (d >= 64) + (d >= 128) + (d >= 256) + (d >= 512);
    meta[4 * L_ + l] = bk;
  }
  const float* a0 = ent_att + (size_t)(b * E_ + i0) * S_;
  const float* a1 = ent_att + (size_t)(b * E_ + i1) * S_;
  const float* m = mask + (size_t)b * S_;
  float v0 = a0[tid] * a1[tid] * m[tid];
  float v1 = a0[tid + 256] * a1[tid + 256] * m[tid + 256];
  float loc = v0 + v1;
  for (int o = 32; o > 0; o >>= 1) loc += __shfl_down(loc, o, 64);
  __shared__ float red[4];
  if ((tid & 63) == 0) red[tid >> 6] = loc;
  __syncthreads();
  float tot = red[0] + red[1] + red[2] + red[3];
  float inv = 1.f / (tot + 1e-20f);
  ht_att[(size_t)l * S_ + tid] = v0 * inv;
  ht_att[(size_t)l * S_ + tid + 256] = v1 * inv;
}

// ---------------------------------------------------------------------------
// K3: ht_info = ht_att @ hs[b]   (per-sample GEMM, M=552, K=512, N=768)
// tiled fp32: BM=BN=64, BK=16, 256 threads, 4x4 per thread
// ---------------------------------------------------------------------------
__global__ void gemm_htinfo(const float* __restrict__ htatt, const float* __restrict__ hs,
                            float* __restrict__ htinfo) {
  int bId = blockIdx.x / 9;
  int m0 = (blockIdx.x % 9) * 64;
  int n0 = blockIdx.y * 64;
  __shared__ float As[16][64];
  __shared__ float Bs[16][64];
  int tid = threadIdx.x;
  int ty = tid / 16, tx = tid % 16;
  float acc[4][4] = {};
  int mmL = tid >> 2, kvL = (tid & 3) * 4;
  int kkB = tid >> 4, nvB = (tid & 15) * 4;
  const float* Bbase = hs + (size_t)bId * S_ * H_;
  for (int k0 = 0; k0 < S_; k0 += 16) {
    float4 a4 = make_float4(0, 0, 0, 0);
    int row = m0 + mmL;
    if (row < P_)
      a4 = *(const float4*)(htatt + ((size_t)(bId * P_ + row)) * S_ + k0 + kvL);
    As[kvL + 0][mmL] = a4.x; As[kvL + 1][mmL] = a4.y;
    As[kvL + 2][mmL] = a4.z; As[kvL + 3][mmL] = a4.w;
    float4 b4 = *(const float4*)(Bbase + (size_t)(k0 + kkB) * H_ + n0 + nvB);
    *(float4*)&Bs[kkB][nvB] = b4;
    __syncthreads();
#pragma unroll
    for (int kk = 0; kk < 16; ++kk) {
      float av[4], bv[4];
#pragma unroll
      for (int i = 0; i < 4; ++i) av[i] = As[kk][ty * 4 + i];
#pragma unroll
      for (int j = 0; j < 4; ++j) bv[j] = Bs[kk][tx * 4 + j];
#pragma unroll
      for (int i = 0; i < 4; ++i)
#pragma unroll
        for (int j = 0; j < 4; ++j) acc[i][j] += av[i] * bv[j];
    }
    __syncthreads();
  }
#pragma unroll
  for (int i = 0; i < 4; ++i) {
    int row = m0 + ty * 4 + i;
    if (row < P_) {
#pragma unroll
      for (int j = 0; j < 4; ++j)
        htinfo[((size_t)(bId * P_ + row)) * H_ + n0 + tx * 4 + j] = acc[i][j];
    }
  }
}

// ---------------------------------------------------------------------------
// K4: h1/t1 = tanh(all_x @ W + b) with all_x gathered on the fly.
// M=2208, K=1576, N=768. Segments: [0,768) ent_feat, [768,1536) ht_info,
// [1536,1556) type_table, [1556,1576) dis_table. All float4-aligned.
// ---------------------------------------------------------------------------
__global__ void gemm_mlp(const float* __restrict__ ent_feat, const float* __restrict__ ht_info,
                         const float* __restrict__ ttab, const float* __restrict__ dtab_f,
                         const int* __restrict__ feat_row, const int* __restrict__ type_row,
                         const int* __restrict__ dist_b,
                         const float* __restrict__ W, const float* __restrict__ bias,
                         float* __restrict__ out) {
  int m0 = blockIdx.x * 64;
  int n0 = blockIdx.y * 64;
  __shared__ float As[16][64];
  __shared__ float Bs[16][64];
  int tid = threadIdx.x;
  int ty = tid / 16, tx = tid % 16;
  float acc[4][4] = {};
  int mmL = tid >> 2, kvL = (tid & 3) * 4;
  int kkB = tid >> 4, nvB = (tid & 15) * 4;
  int lA = m0 + mmL;
  bool rowok = lA < L_;
  int frow = 0, trow = 0, db = 0;
  if (rowok) { frow = feat_row[lA]; trow = type_row[lA]; db = dist_b[lA]; }
  for (int k0 = 0; k0 < DIN_; k0 += 16) {
    int k = k0 + kvL;
    float4 a4 = make_float4(0, 0, 0, 0);
    if (rowok && k < DIN_) {
      if (k < 768)        a4 = *(const float4*)(ent_feat + (size_t)frow * H_ + k);
      else if (k < 1536)  a4 = *(const float4*)(ht_info + (size_t)lA * H_ + (k - 768));
      else if (k < 1556)  a4 = *(const float4*)(ttab + trow * TE_ + (k - 1536));
      else                a4 = *(const float4*)(dtab_f + db * TD_ + (k - 1556));
    }
    As[kvL + 0][mmL] = a4.x; As[kvL + 1][mmL] = a4.y;
    As[kvL + 2][mmL] = a4.z; As[kvL + 3][mmL] = a4.w;
    float4 b4 = make_float4(0, 0, 0, 0);
    int kb = k0 + kkB;
    if (kb < DIN_) b4 = *(const float4*)(W + (size_t)kb * H_ + n0 + nvB);
    *(float4*)&Bs[kkB][nvB] = b4;
    __syncthreads();
#pragma unroll
    for (int kk = 0; kk < 16; ++kk) {
      float av[4], bv[4];
#pragma unroll
      for (int i = 0; i < 4; ++i) av[i] = As[kk][ty * 4 + i];
#pragma unroll
      for (int j = 0; j < 4; ++j) bv[j] = Bs[kk][tx * 4 + j];
#pragma unroll
      for (int i = 0; i < 4; ++i)
#pragma unroll
        for (int j = 0; j < 4; ++j) acc[i][j] += av[i] * bv[j];
    }
    __syncthreads();
  }
#pragma unroll
  for (int i = 0; i < 4; ++i) {
    int l = m0 + ty * 4 + i;
    if (l < L_) {
#pragma unroll
      for (int j = 0; j < 4; ++j) {
        int n = n0 + tx * 4 + j;
        out[(size_t)l * H_ + n] = tanhf(acc[i][j] + bias[n]);
      }
    }
  }
}

// ---------------------------------------------------------------------------
// K5: bilinear classifier partials. logits[l,r] = sum_{n,b,c} x1*x2*clsW.
// Grid (69 m-tiles of 32, 12 n). Writes part[n][l][r] (deterministic, no atomics).
// ---------------------------------------------------------------------------
__global__ void bilinear_part(const float* __restrict__ h1, const float* __restrict__ t1,
                              const float* __restrict__ clsW, float* __restrict__ part) {
  int m0 = blockIdx.x * 32;
  int n = blockIdx.y;
  __shared__ float x1s[32][64];
  __shared__ float x2s[32][64];
  int tid = threadIdx.x;
  for (int i = tid; i < 512; i += 256) {
    int mm = i >> 4, v = (i & 15) * 4;
    *(float4*)&x1s[mm][v] = *(const float4*)(h1 + (size_t)(m0 + mm) * H_ + n * 64 + v);
    *(float4*)&x2s[mm][v] = *(const float4*)(t1 + (size_t)(m0 + mm) * H_ + n * 64 + v);
  }
  __syncthreads();
  int ty = tid / 32;   // rows ty + 8*i
  int tx = tid % 32;   // cols tx + 32*j (j=3 only for tx==0 -> col 96)
  float acc[4][4] = {};
  for (int b = 0; b < 64; ++b) {
    float x1v[4];
#pragma unroll
    for (int i = 0; i < 4; ++i) x1v[i] = x1s[ty + 8 * i][b];
    for (int c = 0; c < 64; ++c) {
      float t[4];
#pragma unroll
      for (int i = 0; i < 4; ++i) t[i] = x1v[i] * x2s[ty + 8 * i][c];
      const float* wp = clsW + (((size_t)n * 64 + b) * 64 + c) * R_;
#pragma unroll
      for (int j = 0; j < 3; ++j) {
        float w = wp[tx + 32 * j];
#pragma unroll
        for (int i = 0; i < 4; ++i) acc[i][j] += t[i] * w;
      }
      if (tx == 0) {
        float w = wp[96];
#pragma unroll
        for (int i = 0; i < 4; ++i) acc[i][3] += t[i] * w;
      }
    }
  }
#pragma unroll
  for (int i = 0; i < 4; ++i) {
    int l = m0 + ty + 8 * i;
#pragma unroll
    for (int j = 0; j < 3; ++j)
      part[((size_t)n * L_ + l) * R_ + tx + 32 * j] = acc[i][j];
    if (tx == 0)
      part[((size_t)n * L_ + l) * R_ + 96] = acc[i][3];
  }
}

// ---------------------------------------------------------------------------
// K6: reduce partials over n, add clsb.
// ---------------------------------------------------------------------------
__global__ void reduce_logits(const float* __restrict__ part, const float* __restrict__ clsb,
                              float* __restrict__ out) {
  int idx = blockIdx.x * 256 + threadIdx.x;
  if (idx < L_ * R_) {
    int r = idx % R_;
    float s = clsb[r];
#pragma unroll
    for (int nn = 0; nn < NB_; ++nn) s += part[(size_t)nn * L_ * R_ + idx];
    out[idx] = s;
  }
}

extern "C" void kernel_launch(void* const* d_in, const int* in_sizes, int n_in,
                              void* d_out, int out_size, void* d_ws, size_t ws_size,
                              hipStream_t stream) {
  const float* hs   = (const float*)d_in[0];
  const float* attn = (const float*)d_in[1];
  const float* mask = (const float*)d_in[2];
  const int*   head = (const int*)d_in[3];
  const int*   tail = (const int*)d_in[4];
  const int*   etyp = (const int*)d_in[5];
  const float* ttab = (const float*)d_in[6];
  const float* dtab = (const float*)d_in[7];
  const float* Wh   = (const float*)d_in[8];
  const float* bh   = (const float*)d_in[9];
  const float* Wt   = (const float*)d_in[10];
  const float* bt   = (const float*)d_in[11];
  const float* clsW = (const float*)d_in[12];
  const float* clsb = (const float*)d_in[13];
  float* out = (float*)d_out;

  float* ws = (float*)d_ws;
  float* ent_att  = ws; ws += (size_t)B_ * E_ * S_;     // 49152
  float* ent_feat = ws; ws += (size_t)B_ * E_ * H_;     // 73728
  float* ht_att   = ws; ws += (size_t)L_ * S_;          // 1130496
  float* ht_info  = ws; ws += (size_t)L_ * H_;          // 1695744
  float* h1       = ws; ws += (size_t)L_ * H_;          // 1695744
  float* t1       = ws; ws += (size_t)L_ * H_;          // 1695744
  float* part     = ws; ws += (size_t)NB_ * L_ * R_;    // 2570112
  int* meta = (int*)ws;                                 // 5*L ints

  ent_prep<<<B_ * E_, 256, 0, stream>>>(attn, hs, head, tail, ent_att, ent_feat);
  pair_att<<<L_, 256, 0, stream>>>(ent_att, mask, head, tail, etyp, ht_att, meta);
  gemm_htinfo<<<dim3(B_ * 9, H_ / 64), 256, 0, stream>>>(ht_att, hs, ht_info);
  gemm_mlp<<<dim3(35, 12), 256, 0, stream>>>(ent_feat, ht_info, ttab, dtab,
      meta + 0 * L_, meta + 2 * L_, meta + 4 * L_, Wh, bh, h1);
  gemm_mlp<<<dim3(35, 12), 256, 0, stream>>>(ent_feat, ht_info, ttab, dtab,
      meta + 1 * L_, meta + 3 * L_, meta + 4 * L_, Wt, bt, t1);
  bilinear_part<<<dim3(69, 12), 256, 0, stream>>>(h1, t1, clsW, part);
  reduce_logits<<<(L_ * R_ + 255) / 256, 256, 0, stream>>>(part, clsb, out);
}

// Round 2
// 392.420 us; speedup vs baseline: 3.6780x; 3.6780x over previous
//
#include <hip/hip_runtime.h>
#include <hip/hip_bf16.h>
#include <math.h>

#define B_ 4
#define S_ 512
#define H_ 768
#define NH_ 12
#define E_ 24
#define TE_ 20
#define TD_ 20
#define R_ 97
#define DIN_ 1576   // 2*H + TE + TD
#define P_ 552      // E*(E-1)
#define L_ 2208     // B*P
#define NB_ 12      // H/64
#define NF_ 7       // n-frags of 16 cols covering 97 -> 112

typedef __bf16 bf16x8 __attribute__((ext_vector_type(8)));
typedef float f32x4 __attribute__((ext_vector_type(4)));

__device__ __forceinline__ unsigned short f2bf(float f) {
  union { float f; unsigned u; } c; c.f = f;
  unsigned r = c.u + 0x7FFF + ((c.u >> 16) & 1);
  return (unsigned short)(r >> 16);
}
__device__ __forceinline__ float bf2f(unsigned short b) {
  union { unsigned u; float f; } c; c.u = ((unsigned)b) << 16;
  return c.f;
}

// ---------------------------------------------------------------------------
// K1: per-entity gathered attention-row sum over heads + entity features.
// ---------------------------------------------------------------------------
__global__ void ent_prep(const float* __restrict__ attn, const float* __restrict__ hs,
                         const int* __restrict__ head, const int* __restrict__ tail,
                         float* __restrict__ ent_att, float* __restrict__ ent_feat) {
  int be = blockIdx.x;
  int b = be / E_;
  int hd = head[be], tl = tail[be];
  int tid = threadIdx.x;
  const float* abase = attn + (size_t)b * NH_ * S_ * S_;
  for (int s = tid; s < S_; s += 256) {
    float acc = 0.f;
#pragma unroll
    for (int nh = 0; nh < NH_; ++nh) {
      const float* ap = abase + (size_t)nh * S_ * S_;
      acc += ap[(size_t)hd * S_ + s] + ap[(size_t)tl * S_ + s];
    }
    ent_att[(size_t)be * S_ + s] = 0.5f * acc;
  }
  const float* hb = hs + (size_t)b * S_ * H_;
  for (int k = tid; k < H_; k += 256) {
    ent_feat[(size_t)be * H_ + k] = 0.5f * (hb[(size_t)hd * H_ + k] + hb[(size_t)tl * H_ + k]);
  }
}

// ---------------------------------------------------------------------------
// K2: pairwise attention product + mask + normalize; pair metadata.
// ---------------------------------------------------------------------------
__global__ void pair_att(const float* __restrict__ ent_att, const float* __restrict__ mask,
                         const int* __restrict__ head, const int* __restrict__ tail,
                         const int* __restrict__ etype,
                         float* __restrict__ ht_att, int* __restrict__ meta) {
  int l = blockIdx.x;
  int b = l / P_, p = l % P_;
  int i0 = p / (E_ - 1), rem = p % (E_ - 1);
  int i1 = rem + (rem >= i0 ? 1 : 0);
  int tid = threadIdx.x;
  if (tid == 0) {
    meta[0 * L_ + l] = b * E_ + i0;
    meta[1 * L_ + l] = b * E_ + i1;
    meta[2 * L_ + l] = etype[b * E_ + i0];
    meta[3 * L_ + l] = etype[b * E_ + i1];
    int d = abs(tail[b * E_ + i0] - head[b * E_ + i1]);
    int bk = (d >= 2) + (d >= 4) + (d >= 8) + (d >= 16) + (d >= 32) +
             (d >= 64) + (d >= 128) + (d >= 256) + (d >= 512);
    meta[4 * L_ + l] = bk;
  }
  const float* a0 = ent_att + (size_t)(b * E_ + i0) * S_;
  const float* a1 = ent_att + (size_t)(b * E_ + i1) * S_;
  const float* m = mask + (size_t)b * S_;
  float v0 = a0[tid] * a1[tid] * m[tid];
  float v1 = a0[tid + 256] * a1[tid + 256] * m[tid + 256];
  float loc = v0 + v1;
  for (int o = 32; o > 0; o >>= 1) loc += __shfl_down(loc, o, 64);
  __shared__ float red[4];
  if ((tid & 63) == 0) red[tid >> 6] = loc;
  __syncthreads();
  float tot = red[0] + red[1] + red[2] + red[3];
  float inv = 1.f / (tot + 1e-20f);
  ht_att[(size_t)l * S_ + tid] = v0 * inv;
  ht_att[(size_t)l * S_ + tid + 256] = v1 * inv;
}

// ---------------------------------------------------------------------------
// K3: ht_info = ht_att @ hs[b]   (M=552, K=512, N=768 per sample, fp32)
// ---------------------------------------------------------------------------
__global__ void gemm_htinfo(const float* __restrict__ htatt, const float* __restrict__ hs,
                            float* __restrict__ htinfo) {
  int bId = blockIdx.x / 9;
  int m0 = (blockIdx.x % 9) * 64;
  int n0 = blockIdx.y * 64;
  __shared__ float As[16][64];
  __shared__ float Bs[16][64];
  int tid = threadIdx.x;
  int ty = tid / 16, tx = tid % 16;
  float acc[4][4] = {};
  int mmL = tid >> 2, kvL = (tid & 3) * 4;
  int kkB = tid >> 4, nvB = (tid & 15) * 4;
  const float* Bbase = hs + (size_t)bId * S_ * H_;
  for (int k0 = 0; k0 < S_; k0 += 16) {
    float4 a4 = make_float4(0, 0, 0, 0);
    int row = m0 + mmL;
    if (row < P_)
      a4 = *(const float4*)(htatt + ((size_t)(bId * P_ + row)) * S_ + k0 + kvL);
    As[kvL + 0][mmL] = a4.x; As[kvL + 1][mmL] = a4.y;
    As[kvL + 2][mmL] = a4.z; As[kvL + 3][mmL] = a4.w;
    float4 b4 = *(const float4*)(Bbase + (size_t)(k0 + kkB) * H_ + n0 + nvB);
    *(float4*)&Bs[kkB][nvB] = b4;
    __syncthreads();
#pragma unroll
    for (int kk = 0; kk < 16; ++kk) {
      float av[4], bv[4];
#pragma unroll
      for (int i = 0; i < 4; ++i) av[i] = As[kk][ty * 4 + i];
#pragma unroll
      for (int j = 0; j < 4; ++j) bv[j] = Bs[kk][tx * 4 + j];
#pragma unroll
      for (int i = 0; i < 4; ++i)
#pragma unroll
        for (int j = 0; j < 4; ++j) acc[i][j] += av[i] * bv[j];
    }
    __syncthreads();
  }
#pragma unroll
  for (int i = 0; i < 4; ++i) {
    int row = m0 + ty * 4 + i;
    if (row < P_) {
#pragma unroll
      for (int j = 0; j < 4; ++j)
        htinfo[((size_t)(bId * P_ + row)) * H_ + n0 + tx * 4 + j] = acc[i][j];
    }
  }
}

// ---------------------------------------------------------------------------
// K4: h1/t1 = tanh(all_x @ W + b), all_x gathered on the fly (fp32)
// ---------------------------------------------------------------------------
__global__ void gemm_mlp(const float* __restrict__ ent_feat, const float* __restrict__ ht_info,
                         const float* __restrict__ ttab, const float* __restrict__ dtab_f,
                         const int* __restrict__ feat_row, const int* __restrict__ type_row,
                         const int* __restrict__ dist_b,
                         const float* __restrict__ W, const float* __restrict__ bias,
                         float* __restrict__ out) {
  int m0 = blockIdx.x * 64;
  int n0 = blockIdx.y * 64;
  __shared__ float As[16][64];
  __shared__ float Bs[16][64];
  int tid = threadIdx.x;
  int ty = tid / 16, tx = tid % 16;
  float acc[4][4] = {};
  int mmL = tid >> 2, kvL = (tid & 3) * 4;
  int kkB = tid >> 4, nvB = (tid & 15) * 4;
  int lA = m0 + mmL;
  bool rowok = lA < L_;
  int frow = 0, trow = 0, db = 0;
  if (rowok) { frow = feat_row[lA]; trow = type_row[lA]; db = dist_b[lA]; }
  for (int k0 = 0; k0 < DIN_; k0 += 16) {
    int k = k0 + kvL;
    float4 a4 = make_float4(0, 0, 0, 0);
    if (rowok && k < DIN_) {
      if (k < 768)        a4 = *(const float4*)(ent_feat + (size_t)frow * H_ + k);
      else if (k < 1536)  a4 = *(const float4*)(ht_info + (size_t)lA * H_ + (k - 768));
      else if (k < 1556)  a4 = *(const float4*)(ttab + trow * TE_ + (k - 1536));
      else                a4 = *(const float4*)(dtab_f + db * TD_ + (k - 1556));
    }
    As[kvL + 0][mmL] = a4.x; As[kvL + 1][mmL] = a4.y;
    As[kvL + 2][mmL] = a4.z; As[kvL + 3][mmL] = a4.w;
    float4 b4 = make_float4(0, 0, 0, 0);
    int kb = k0 + kkB;
    if (kb < DIN_) b4 = *(const float4*)(W + (size_t)kb * H_ + n0 + nvB);
    *(float4*)&Bs[kkB][nvB] = b4;
    __syncthreads();
#pragma unroll
    for (int kk = 0; kk < 16; ++kk) {
      float av[4], bv[4];
#pragma unroll
      for (int i = 0; i < 4; ++i) av[i] = As[kk][ty * 4 + i];
#pragma unroll
      for (int j = 0; j < 4; ++j) bv[j] = Bs[kk][tx * 4 + j];
#pragma unroll
      for (int i = 0; i < 4; ++i)
#pragma unroll
        for (int j = 0; j < 4; ++j) acc[i][j] += av[i] * bv[j];
    }
    __syncthreads();
  }
#pragma unroll
  for (int i = 0; i < 4; ++i) {
    int l = m0 + ty * 4 + i;
    if (l < L_) {
#pragma unroll
      for (int j = 0; j < 4; ++j) {
        int n = n0 + tx * 4 + j;
        out[(size_t)l * H_ + n] = tanhf(acc[i][j] + bias[n]);
      }
    }
  }
}

// ---------------------------------------------------------------------------
// K5a: pre-pack clsW -> fragment-major bf16 layout for MFMA B-operand.
// Wfrag unit u in [0,896) per (n,b): nf=u/128, kc=(u/64)&1, lane=u&63.
// Element j (0..7): c = (lane>>4)*8 + j + 32*kc ; r = (lane&15) + 16*nf.
// One block per (n,b). Out: uint4 per unit (8 bf16).
// ---------------------------------------------------------------------------
__global__ void pack_w(const float* __restrict__ clsW, uint4* __restrict__ Wfrag) {
  int nb = blockIdx.x;            // n*64 + b
  __shared__ float Wls[64][98];   // [c][r], padded
  int tid = threadIdx.x;
  const float* src = clsW + (size_t)nb * 64 * R_;
  for (int idx = tid; idx < 64 * R_; idx += 256) {
    Wls[idx / R_][idx % R_] = src[idx];
  }
  __syncthreads();
  for (int u = tid; u < 896; u += 256) {
    int nf = u >> 7;
    int kc = (u >> 6) & 1;
    int lane = u & 63;
    int r = (lane & 15) + 16 * nf;
    unsigned w[4];
#pragma unroll
    for (int q = 0; q < 4; ++q) {
      int c0 = ((lane >> 4) << 3) + 2 * q + 32 * kc;
      float v0 = (r < R_) ? Wls[c0][r] : 0.f;
      float v1 = (r < R_) ? Wls[c0 + 1][r] : 0.f;
      w[q] = (unsigned)f2bf(v0) | ((unsigned)f2bf(v1) << 16);
    }
    uint4 o; o.x = w[0]; o.y = w[1]; o.z = w[2]; o.w = w[3];
    Wfrag[(size_t)nb * 896 + u] = o;
  }
}

// ---------------------------------------------------------------------------
// K5b: bilinear as bf16 MFMA GEMM. Per block: 64 l-rows x one n (K=4096).
// 2 waves, each 32 rows (2 m-frags) x 112 cols (7 n-frags).
// A[l, (b,c)] = x1[l,b]*x2[l,c] composed in registers (x2 frags loop-invariant).
// W double-buffered in LDS via reg staging, one barrier per K-step.
// ---------------------------------------------------------------------------
__global__ __launch_bounds__(128) void bilinear_mfma(
    const float* __restrict__ h1, const float* __restrict__ t1,
    const uint4* __restrict__ Wfrag, float* __restrict__ part) {
  int n = blockIdx.y;
  int l0 = blockIdx.x * 64;
  int tid = threadIdx.x;
  int wave = tid >> 6, lane = tid & 63;
  __shared__ uint4 Wl[2][896];
  __shared__ unsigned short x1s[64][64];   // [b][l-within-tile], bf16 bits

  // x1 tile -> LDS (transposed), bf16
  for (int i = tid; i < 1024; i += 128) {
    int l = i >> 4, bq = (i & 15) * 4;
    float4 v = make_float4(0, 0, 0, 0);
    if (l0 + l < L_) v = *(const float4*)(h1 + (size_t)(l0 + l) * H_ + n * 64 + bq);
    x1s[bq + 0][l] = f2bf(v.x);
    x1s[bq + 1][l] = f2bf(v.y);
    x1s[bq + 2][l] = f2bf(v.z);
    x1s[bq + 3][l] = f2bf(v.w);
  }

  // x2 fragments (loop-invariant per n): f32 regs
  float x2f[2][2][8];
#pragma unroll
  for (int mf = 0; mf < 2; ++mf) {
    int row = l0 + wave * 32 + mf * 16 + (lane & 15);
#pragma unroll
    for (int kc = 0; kc < 2; ++kc) {
      float4 v0 = make_float4(0, 0, 0, 0), v1 = v0;
      if (row < L_) {
        const float* p = t1 + (size_t)row * H_ + n * 64 + kc * 32 + ((lane >> 4) << 3);
        v0 = *(const float4*)p;
        v1 = *(const float4*)(p + 4);
      }
      x2f[mf][kc][0] = v0.x; x2f[mf][kc][1] = v0.y;
      x2f[mf][kc][2] = v0.z; x2f[mf][kc][3] = v0.w;
      x2f[mf][kc][4] = v1.x; x2f[mf][kc][5] = v1.y;
      x2f[mf][kc][6] = v1.z; x2f[mf][kc][7] = v1.w;
    }
  }

  f32x4 acc[2][NF_];
#pragma unroll
  for (int mf = 0; mf < 2; ++mf)
#pragma unroll
    for (int nf = 0; nf < NF_; ++nf)
      acc[mf][nf] = (f32x4){0.f, 0.f, 0.f, 0.f};

  // prologue: stage b=0
  uint4 st[7];
  {
    const uint4* gs = Wfrag + (size_t)(n * 64 + 0) * 896;
#pragma unroll
    for (int r = 0; r < 7; ++r) st[r] = gs[tid + r * 128];
#pragma unroll
    for (int r = 0; r < 7; ++r) Wl[0][tid + r * 128] = st[r];
  }
  __syncthreads();

  for (int b = 0; b < 64; ++b) {
    int cur = b & 1, nxt = cur ^ 1;
    if (b + 1 < 64) {
      const uint4* gs = Wfrag + (size_t)(n * 64 + b + 1) * 896;
#pragma unroll
      for (int r = 0; r < 7; ++r) st[r] = gs[tid + r * 128];
    }
    // compose A-fragments for this b
    bf16x8 afr[2][2];
#pragma unroll
    for (int mf = 0; mf < 2; ++mf) {
      float x1v = bf2f(x1s[b][wave * 32 + mf * 16 + (lane & 15)]);
#pragma unroll
      for (int kc = 0; kc < 2; ++kc)
#pragma unroll
        for (int j = 0; j < 8; ++j)
          afr[mf][kc][j] = (__bf16)(x1v * x2f[mf][kc][j]);
    }
    // MFMAs
#pragma unroll
    for (int nf = 0; nf < NF_; ++nf) {
#pragma unroll
      for (int kc = 0; kc < 2; ++kc) {
        bf16x8 bfr = *(const bf16x8*)&Wl[cur][(nf * 2 + kc) * 64 + lane];
#pragma unroll
        for (int mf = 0; mf < 2; ++mf)
          acc[mf][nf] = __builtin_amdgcn_mfma_f32_16x16x32_bf16(
              afr[mf][kc], bfr, acc[mf][nf], 0, 0, 0);
      }
    }
    if (b + 1 < 64) {
#pragma unroll
      for (int r = 0; r < 7; ++r) Wl[nxt][tid + r * 128] = st[r];
    }
    __syncthreads();
  }

  // epilogue: C/D layout col=lane&15, row=(lane>>4)*4+reg
#pragma unroll
  for (int mf = 0; mf < 2; ++mf) {
#pragma unroll
    for (int nf = 0; nf < NF_; ++nf) {
      int r = nf * 16 + (lane & 15);
      if (r < R_) {
#pragma unroll
        for (int reg = 0; reg < 4; ++reg) {
          int l = l0 + wave * 32 + mf * 16 + ((lane >> 4) << 2) + reg;
          if (l < L_)
            part[((size_t)n * L_ + l) * R_ + r] = acc[mf][nf][reg];
        }
      }
    }
  }
}

// ---------------------------------------------------------------------------
// K6: reduce partials over n, add clsb.
// ---------------------------------------------------------------------------
__global__ void reduce_logits(const float* __restrict__ part, const float* __restrict__ clsb,
                              float* __restrict__ out) {
  int idx = blockIdx.x * 256 + threadIdx.x;
  if (idx < L_ * R_) {
    int r = idx % R_;
    float s = clsb[r];
#pragma unroll
    for (int nn = 0; nn < NB_; ++nn) s += part[(size_t)nn * L_ * R_ + idx];
    out[idx] = s;
  }
}

extern "C" void kernel_launch(void* const* d_in, const int* in_sizes, int n_in,
                              void* d_out, int out_size, void* d_ws, size_t ws_size,
                              hipStream_t stream) {
  const float* hs   = (const float*)d_in[0];
  const float* attn = (const float*)d_in[1];
  const float* mask = (const float*)d_in[2];
  const int*   head = (const int*)d_in[3];
  const int*   tail = (const int*)d_in[4];
  const int*   etyp = (const int*)d_in[5];
  const float* ttab = (const float*)d_in[6];
  const float* dtab = (const float*)d_in[7];
  const float* Wh   = (const float*)d_in[8];
  const float* bh   = (const float*)d_in[9];
  const float* Wt   = (const float*)d_in[10];
  const float* bt   = (const float*)d_in[11];
  const float* clsW = (const float*)d_in[12];
  const float* clsb = (const float*)d_in[13];
  float* out = (float*)d_out;

  float* ws = (float*)d_ws;
  float* ent_att  = ws; ws += (size_t)B_ * E_ * S_;     // 49152
  float* ent_feat = ws; ws += (size_t)B_ * E_ * H_;     // 73728
  float* ht_att   = ws; ws += (size_t)L_ * S_;          // 1130496
  float* ht_info  = ws; ws += (size_t)L_ * H_;          // 1695744
  float* h1       = ws; ws += (size_t)L_ * H_;          // 1695744
  float* t1       = ws; ws += (size_t)L_ * H_;          // 1695744
  float* part     = ws; ws += (size_t)NB_ * L_ * R_;    // 2570112
  int* meta = (int*)ws;                                 // 5*L ints
  // Wfrag (11 MB, bf16 frag-major) aliases ht_att+ht_info, which are dead
  // after the two gemm_mlp launches. pack_w runs after them.
  uint4* Wfrag = (uint4*)ht_att;

  ent_prep<<<B_ * E_, 256, 0, stream>>>(attn, hs, head, tail, ent_att, ent_feat);
  pair_att<<<L_, 256, 0, stream>>>(ent_att, mask, head, tail, etyp, ht_att, meta);
  gemm_htinfo<<<dim3(B_ * 9, H_ / 64), 256, 0, stream>>>(ht_att, hs, ht_info);
  gemm_mlp<<<dim3(35, 12), 256, 0, stream>>>(ent_feat, ht_info, ttab, dtab,
      meta + 0 * L_, meta + 2 * L_, meta + 4 * L_, Wh, bh, h1);
  gemm_mlp<<<dim3(35, 12), 256, 0, stream>>>(ent_feat, ht_info, ttab, dtab,
      meta + 1 * L_, meta + 3 * L_, meta + 4 * L_, Wt, bt, t1);
  pack_w<<<NB_ * 64, 256, 0, stream>>>(clsW, Wfrag);
  bilinear_mfma<<<dim3(35, NB_), 128, 0, stream>>>(h1, t1, Wfrag, part);
  reduce_logits<<<(L_ * R_ + 255) / 256, 256, 0, stream>>>(part, clsb, out);
}

// Round 3
// 178.356 us; speedup vs baseline: 8.0923x; 2.2002x over previous
//
#include <hip/hip_runtime.h>
#include <hip/hip_bf16.h>
#include <math.h>

#define B_ 4
#define S_ 512
#define H_ 768
#define NH_ 12
#define E_ 24
#define TE_ 20
#define TD_ 20
#define R_ 97
#define DIN_ 1576   // 2*H + TE + TD
#define KPAD_ 1600  // DIN padded to multiple of 32
#define KS_MLP 50   // KPAD/32
#define KS_HTI 16   // 512/32
#define P_ 552      // E*(E-1)
#define L_ 2208     // B*P
#define NB_ 12      // H/64
#define NF_ 7       // n-frags of 16 cols covering 97 -> 112

typedef __bf16 bf16x8 __attribute__((ext_vector_type(8)));
typedef float f32x4 __attribute__((ext_vector_type(4)));

__device__ __forceinline__ unsigned short f2bf(float f) {
  union { float f; unsigned u; } c; c.f = f;
  unsigned r = c.u + 0x7FFF + ((c.u >> 16) & 1);
  return (unsigned short)(r >> 16);
}
__device__ __forceinline__ float bf2f(unsigned short b) {
  union { unsigned u; float f; } c; c.u = ((unsigned)b) << 16;
  return c.f;
}
__device__ __forceinline__ unsigned pk2(float a, float b) {
  return (unsigned)f2bf(a) | ((unsigned)f2bf(b) << 16);
}

// ---------------------------------------------------------------------------
// K1: per-entity gathered attention-row sum over heads + entity features.
// ---------------------------------------------------------------------------
__global__ void ent_prep(const float* __restrict__ attn, const float* __restrict__ hs,
                         const int* __restrict__ head, const int* __restrict__ tail,
                         float* __restrict__ ent_att, float* __restrict__ ent_feat) {
  int be = blockIdx.x;
  int b = be / E_;
  int hd = head[be], tl = tail[be];
  int tid = threadIdx.x;
  const float* abase = attn + (size_t)b * NH_ * S_ * S_;
  for (int s = tid; s < S_; s += 256) {
    float acc = 0.f;
#pragma unroll
    for (int nh = 0; nh < NH_; ++nh) {
      const float* ap = abase + (size_t)nh * S_ * S_;
      acc += ap[(size_t)hd * S_ + s] + ap[(size_t)tl * S_ + s];
    }
    ent_att[(size_t)be * S_ + s] = 0.5f * acc;
  }
  const float* hb = hs + (size_t)b * S_ * H_;
  for (int k = tid; k < H_; k += 256) {
    ent_feat[(size_t)be * H_ + k] = 0.5f * (hb[(size_t)hd * H_ + k] + hb[(size_t)tl * H_ + k]);
  }
}

// ---------------------------------------------------------------------------
// K2: pairwise attention product + mask + normalize; pair metadata.
// ---------------------------------------------------------------------------
__global__ void pair_att(const float* __restrict__ ent_att, const float* __restrict__ mask,
                         const int* __restrict__ head, const int* __restrict__ tail,
                         const int* __restrict__ etype,
                         float* __restrict__ ht_att, int* __restrict__ meta) {
  int l = blockIdx.x;
  int b = l / P_, p = l % P_;
  int i0 = p / (E_ - 1), rem = p % (E_ - 1);
  int i1 = rem + (rem >= i0 ? 1 : 0);
  int tid = threadIdx.x;
  if (tid == 0) {
    meta[0 * L_ + l] = b * E_ + i0;
    meta[1 * L_ + l] = b * E_ + i1;
    meta[2 * L_ + l] = etype[b * E_ + i0];
    meta[3 * L_ + l] = etype[b * E_ + i1];
    int d = abs(tail[b * E_ + i0] - head[b * E_ + i1]);
    int bk = (d >= 2) + (d >= 4) + (d >= 8) + (d >= 16) + (d >= 32) +
             (d >= 64) + (d >= 128) + (d >= 256) + (d >= 512);
    meta[4 * L_ + l] = bk;
  }
  const float* a0 = ent_att + (size_t)(b * E_ + i0) * S_;
  const float* a1 = ent_att + (size_t)(b * E_ + i1) * S_;
  const float* m = mask + (size_t)b * S_;
  float v0 = a0[tid] * a1[tid] * m[tid];
  float v1 = a0[tid + 256] * a1[tid + 256] * m[tid + 256];
  float loc = v0 + v1;
  for (int o = 32; o > 0; o >>= 1) loc += __shfl_down(loc, o, 64);
  __shared__ float red[4];
  if ((tid & 63) == 0) red[tid >> 6] = loc;
  __syncthreads();
  float tot = red[0] + red[1] + red[2] + red[3];
  float inv = 1.f / (tot + 1e-20f);
  ht_att[(size_t)l * S_ + tid] = v0 * inv;
  ht_att[(size_t)l * S_ + tid + 256] = v1 * inv;
}

// ---------------------------------------------------------------------------
// pack_hs: hs (B,S,H f32) -> bf16 fragment-major [b][ks][nt16][lane][8]
// unit element j: k = ks*32 + (lane>>4)*8 + j ; n = nt16*16 + (lane&15)
// ---------------------------------------------------------------------------
__global__ void pack_hs(const float* __restrict__ hs, uint4* __restrict__ hsP) {
  int u = blockIdx.x * 256 + threadIdx.x;
  if (u >= B_ * KS_HTI * 48 * 64) return;
  int lane = u & 63;
  int t = u >> 6;
  int nt16 = t % 48;
  int t2 = t / 48;
  int ks = t2 % KS_HTI;
  int b = t2 / KS_HTI;
  int n = nt16 * 16 + (lane & 15);
  int k0 = ks * 32 + ((lane >> 4) << 3);
  const float* src = hs + (size_t)b * S_ * H_;
  unsigned w[4];
#pragma unroll
  for (int q = 0; q < 4; ++q) {
    int k = k0 + 2 * q;
    w[q] = pk2(src[(size_t)k * H_ + n], src[(size_t)(k + 1) * H_ + n]);
  }
  uint4 o; o.x = w[0]; o.y = w[1]; o.z = w[2]; o.w = w[3];
  hsP[u] = o;
}

// ---------------------------------------------------------------------------
// pack_Wmlp: W (DIN,H f32) -> bf16 fragment-major [ks][nt16][lane][8], k>=DIN -> 0
// ---------------------------------------------------------------------------
__global__ void pack_Wmlp(const float* __restrict__ W, uint4* __restrict__ Wp) {
  int u = blockIdx.x * 256 + threadIdx.x;
  if (u >= KS_MLP * 48 * 64) return;
  int lane = u & 63;
  int t = u >> 6;
  int nt16 = t % 48;
  int ks = t / 48;
  int n = nt16 * 16 + (lane & 15);
  int k0 = ks * 32 + ((lane >> 4) << 3);
  unsigned w[4];
#pragma unroll
  for (int q = 0; q < 4; ++q) {
    int k = k0 + 2 * q;
    float v0 = (k < DIN_) ? W[(size_t)k * H_ + n] : 0.f;
    float v1 = (k + 1 < DIN_) ? W[(size_t)(k + 1) * H_ + n] : 0.f;
    w[q] = pk2(v0, v1);
  }
  uint4 o; o.x = w[0]; o.y = w[1]; o.z = w[2]; o.w = w[3];
  Wp[u] = o;
}

// ---------------------------------------------------------------------------
// htinfo_mfma: ht_info = ht_att @ hs[b], bf16 MFMA.
// BM=64 BN=128 BK=32, 4 waves (2m x 2n), per-wave 32x64 (2 mfrag x 4 nfrag).
// A reg-staged (f32->bf16 cvt), B from hsP linear.
// ---------------------------------------------------------------------------
__global__ __launch_bounds__(256) void htinfo_mfma(
    const float* __restrict__ htatt, const uint4* __restrict__ hsP,
    float* __restrict__ htinfo) {
  int b = blockIdx.z;
  int m0 = blockIdx.x * 64;
  int n0 = blockIdx.y * 128;
  int tid = threadIdx.x;
  int wave = tid >> 6, lane = tid & 63;
  int wm = wave & 1, wn = wave >> 1;
  __shared__ __align__(16) unsigned short Ash[2][2048];
  __shared__ __align__(16) unsigned short Bsh[2][4096];

  int amt = tid >> 6, alane = tid & 63;
  int arow = m0 + amt * 16 + (alane & 15);
  bool rowok = arow < P_;
  const float* ap = htatt + ((size_t)b * P_ + (rowok ? arow : 0)) * S_;
  int akoff = (alane >> 4) << 3;
  int nt0 = n0 >> 4;

  f32x4 acc[2][4];
#pragma unroll
  for (int i = 0; i < 2; ++i)
#pragma unroll
    for (int j = 0; j < 4; ++j) acc[i][j] = (f32x4){0.f, 0.f, 0.f, 0.f};

  // prologue: stage ks=0
  {
    uint4 aU; size_t gb = ((size_t)(b * KS_HTI + 0) * 48 + nt0) * 64;
    uint4 b0 = hsP[gb + tid], b1 = hsP[gb + 256 + tid];
    if (rowok) {
      float4 v0 = *(const float4*)(ap + akoff);
      float4 v1 = *(const float4*)(ap + akoff + 4);
      aU.x = pk2(v0.x, v0.y); aU.y = pk2(v0.z, v0.w);
      aU.z = pk2(v1.x, v1.y); aU.w = pk2(v1.z, v1.w);
    } else aU.x = aU.y = aU.z = aU.w = 0;
    *(uint4*)&Ash[0][tid * 8] = aU;
    *(uint4*)&Bsh[0][tid * 8] = b0;
    *(uint4*)&Bsh[0][tid * 8 + 2048] = b1;
  }
  __syncthreads();

  for (int ks = 0; ks < KS_HTI; ++ks) {
    int cur = ks & 1, nxt = cur ^ 1;
    bool more = (ks + 1 < KS_HTI);
    uint4 aN, bN0, bN1;
    if (more) {
      size_t gb = ((size_t)(b * KS_HTI + ks + 1) * 48 + nt0) * 64;
      bN0 = hsP[gb + tid]; bN1 = hsP[gb + 256 + tid];
      int k = (ks + 1) * 32 + akoff;
      if (rowok) {
        float4 v0 = *(const float4*)(ap + k);
        float4 v1 = *(const float4*)(ap + k + 4);
        aN.x = pk2(v0.x, v0.y); aN.y = pk2(v0.z, v0.w);
        aN.z = pk2(v1.x, v1.y); aN.w = pk2(v1.z, v1.w);
      } else aN.x = aN.y = aN.z = aN.w = 0;
    }
    bf16x8 af[2], bf[4];
#pragma unroll
    for (int mf = 0; mf < 2; ++mf)
      af[mf] = *(const bf16x8*)&Ash[cur][((wm * 2 + mf) * 64 + lane) * 8];
#pragma unroll
    for (int nf = 0; nf < 4; ++nf)
      bf[nf] = *(const bf16x8*)&Bsh[cur][((wn * 4 + nf) * 64 + lane) * 8];
#pragma unroll
    for (int nf = 0; nf < 4; ++nf)
#pragma unroll
      for (int mf = 0; mf < 2; ++mf)
        acc[mf][nf] = __builtin_amdgcn_mfma_f32_16x16x32_bf16(af[mf], bf[nf], acc[mf][nf], 0, 0, 0);
    if (more) {
      *(uint4*)&Ash[nxt][tid * 8] = aN;
      *(uint4*)&Bsh[nxt][tid * 8] = bN0;
      *(uint4*)&Bsh[nxt][tid * 8 + 2048] = bN1;
    }
    __syncthreads();
  }

#pragma unroll
  for (int mf = 0; mf < 2; ++mf)
#pragma unroll
    for (int nf = 0; nf < 4; ++nf) {
      int n = n0 + (wn * 4 + nf) * 16 + (lane & 15);
#pragma unroll
      for (int reg = 0; reg < 4; ++reg) {
        int l = m0 + (wm * 2 + mf) * 16 + ((lane >> 4) << 2) + reg;
        if (l < P_)
          htinfo[((size_t)b * P_ + l) * H_ + n] = acc[mf][nf][reg];
      }
    }
}

// ---------------------------------------------------------------------------
// mlp_mfma: h1/t1 = tanh(all_x @ W + b). M=2208(pad 2240), K=1600, N=768.
// A gathered+cvt in regs per K-step; B from Wpack linear. z = half (h/t).
// ---------------------------------------------------------------------------
__global__ __launch_bounds__(256) void mlp_mfma(
    const float* __restrict__ ent_feat, const float* __restrict__ ht_info,
    const float* __restrict__ ttab, const float* __restrict__ dtab,
    const int* __restrict__ meta,
    const uint4* __restrict__ Wp_h, const uint4* __restrict__ Wp_t,
    const float* __restrict__ bh, const float* __restrict__ bt,
    float* __restrict__ h1, float* __restrict__ t1) {
  int half = blockIdx.z;
  const uint4* Wp = half ? Wp_t : Wp_h;
  const float* bias = half ? bt : bh;
  float* out = half ? t1 : h1;
  const int* feat_row = meta + half * L_;
  const int* type_row = meta + (2 + half) * L_;
  const int* distb = meta + 4 * L_;

  int l0 = blockIdx.x * 64;
  int n0 = blockIdx.y * 128;
  int tid = threadIdx.x;
  int wave = tid >> 6, lane = tid & 63;
  int wm = wave & 1, wn = wave >> 1;
  __shared__ __align__(16) unsigned short Ash[2][2048];
  __shared__ __align__(16) unsigned short Bsh[2][4096];

  int amt = tid >> 6, alane = tid & 63;
  int arow = l0 + amt * 16 + (alane & 15);
  bool rowok = arow < L_;
  int frow = 0, trow = 0, db = 0;
  if (rowok) { frow = feat_row[arow]; trow = type_row[arow]; db = distb[arow]; }
  const float* efp = ent_feat + (size_t)frow * H_;
  const float* hip_ = ht_info + (size_t)arow * H_;
  int akoff = (alane >> 4) << 3;
  int nt0 = n0 >> 4;

  f32x4 acc[2][4];
#pragma unroll
  for (int i = 0; i < 2; ++i)
#pragma unroll
    for (int j = 0; j < 4; ++j) acc[i][j] = (f32x4){0.f, 0.f, 0.f, 0.f};

  // gather 8 bf16 of gathered row at k (k % 8 == 0, k-block never crosses segs)
  auto gatherA = [&](int ks, uint4& d) {
    int k = ks * 32 + akoff;
    if (!rowok) { d.x = d.y = d.z = d.w = 0; return; }
    if (k < 768) {
      float4 v0 = *(const float4*)(efp + k);
      float4 v1 = *(const float4*)(efp + k + 4);
      d.x = pk2(v0.x, v0.y); d.y = pk2(v0.z, v0.w);
      d.z = pk2(v1.x, v1.y); d.w = pk2(v1.z, v1.w);
    } else if (k < 1536) {
      float4 v0 = *(const float4*)(hip_ + k - 768);
      float4 v1 = *(const float4*)(hip_ + k - 764);
      d.x = pk2(v0.x, v0.y); d.y = pk2(v0.z, v0.w);
      d.z = pk2(v1.x, v1.y); d.w = pk2(v1.z, v1.w);
    } else {
      float v[8];
#pragma unroll
      for (int j = 0; j < 8; ++j) {
        int e = k + j;
        v[j] = (e < 1556) ? ttab[trow * TE_ + (e - 1536)]
             : (e < 1576) ? dtab[db * TD_ + (e - 1556)] : 0.f;
      }
      d.x = pk2(v[0], v[1]); d.y = pk2(v[2], v[3]);
      d.z = pk2(v[4], v[5]); d.w = pk2(v[6], v[7]);
    }
  };

  // prologue: stage ks=0
  {
    uint4 aU; gatherA(0, aU);
    size_t gb = ((size_t)0 * 48 + nt0) * 64;
    uint4 b0 = Wp[gb + tid], b1 = Wp[gb + 256 + tid];
    *(uint4*)&Ash[0][tid * 8] = aU;
    *(uint4*)&Bsh[0][tid * 8] = b0;
    *(uint4*)&Bsh[0][tid * 8 + 2048] = b1;
  }
  __syncthreads();

  for (int ks = 0; ks < KS_MLP; ++ks) {
    int cur = ks & 1, nxt = cur ^ 1;
    bool more = (ks + 1 < KS_MLP);
    uint4 aN, bN0, bN1;
    if (more) {
      size_t gb = ((size_t)(ks + 1) * 48 + nt0) * 64;
      bN0 = Wp[gb + tid]; bN1 = Wp[gb + 256 + tid];
      gatherA(ks + 1, aN);
    }
    bf16x8 af[2], bf[4];
#pragma unroll
    for (int mf = 0; mf < 2; ++mf)
      af[mf] = *(const bf16x8*)&Ash[cur][((wm * 2 + mf) * 64 + lane) * 8];
#pragma unroll
    for (int nf = 0; nf < 4; ++nf)
      bf[nf] = *(const bf16x8*)&Bsh[cur][((wn * 4 + nf) * 64 + lane) * 8];
#pragma unroll
    for (int nf = 0; nf < 4; ++nf)
#pragma unroll
      for (int mf = 0; mf < 2; ++mf)
        acc[mf][nf] = __builtin_amdgcn_mfma_f32_16x16x32_bf16(af[mf], bf[nf], acc[mf][nf], 0, 0, 0);
    if (more) {
      *(uint4*)&Ash[nxt][tid * 8] = aN;
      *(uint4*)&Bsh[nxt][tid * 8] = bN0;
      *(uint4*)&Bsh[nxt][tid * 8 + 2048] = bN1;
    }
    __syncthreads();
  }

#pragma unroll
  for (int mf = 0; mf < 2; ++mf)
#pragma unroll
    for (int nf = 0; nf < 4; ++nf) {
      int n = n0 + (wn * 4 + nf) * 16 + (lane & 15);
      float bv = bias[n];
#pragma unroll
      for (int reg = 0; reg < 4; ++reg) {
        int l = l0 + (wm * 2 + mf) * 16 + ((lane >> 4) << 2) + reg;
        if (l < L_)
          out[(size_t)l * H_ + n] = tanhf(acc[mf][nf][reg] + bv);
      }
    }
}

// ---------------------------------------------------------------------------
// K5a: pre-pack clsW -> fragment-major bf16 for the bilinear B-operand.
// ---------------------------------------------------------------------------
__global__ void pack_w(const float* __restrict__ clsW, uint4* __restrict__ Wfrag) {
  int nb = blockIdx.x;            // n*64 + b
  __shared__ float Wls[64][98];
  int tid = threadIdx.x;
  const float* src = clsW + (size_t)nb * 64 * R_;
  for (int idx = tid; idx < 64 * R_; idx += 256) {
    Wls[idx / R_][idx % R_] = src[idx];
  }
  __syncthreads();
  for (int u = tid; u < 896; u += 256) {
    int nf = u >> 7;
    int kc = (u >> 6) & 1;
    int lane = u & 63;
    int r = (lane & 15) + 16 * nf;
    unsigned w[4];
#pragma unroll
    for (int q = 0; q < 4; ++q) {
      int c0 = ((lane >> 4) << 3) + 2 * q + 32 * kc;
      float v0 = (r < R_) ? Wls[c0][r] : 0.f;
      float v1 = (r < R_) ? Wls[c0 + 1][r] : 0.f;
      w[q] = (unsigned)f2bf(v0) | ((unsigned)f2bf(v1) << 16);
    }
    uint4 o; o.x = w[0]; o.y = w[1]; o.z = w[2]; o.w = w[3];
    Wfrag[(size_t)nb * 896 + u] = o;
  }
}

// ---------------------------------------------------------------------------
// K5b: bilinear as bf16 MFMA GEMM (as R2, unchanged).
// ---------------------------------------------------------------------------
__global__ __launch_bounds__(128) void bilinear_mfma(
    const float* __restrict__ h1, const float* __restrict__ t1,
    const uint4* __restrict__ Wfrag, float* __restrict__ part) {
  int n = blockIdx.y;
  int l0 = blockIdx.x * 64;
  int tid = threadIdx.x;
  int wave = tid >> 6, lane = tid & 63;
  __shared__ uint4 Wl[2][896];
  __shared__ unsigned short x1s[64][64];

  for (int i = tid; i < 1024; i += 128) {
    int l = i >> 4, bq = (i & 15) * 4;
    float4 v = make_float4(0, 0, 0, 0);
    if (l0 + l < L_) v = *(const float4*)(h1 + (size_t)(l0 + l) * H_ + n * 64 + bq);
    x1s[bq + 0][l] = f2bf(v.x);
    x1s[bq + 1][l] = f2bf(v.y);
    x1s[bq + 2][l] = f2bf(v.z);
    x1s[bq + 3][l] = f2bf(v.w);
  }

  float x2f[2][2][8];
#pragma unroll
  for (int mf = 0; mf < 2; ++mf) {
    int row = l0 + wave * 32 + mf * 16 + (lane & 15);
#pragma unroll
    for (int kc = 0; kc < 2; ++kc) {
      float4 v0 = make_float4(0, 0, 0, 0), v1 = v0;
      if (row < L_) {
        const float* p = t1 + (size_t)row * H_ + n * 64 + kc * 32 + ((lane >> 4) << 3);
        v0 = *(const float4*)p;
        v1 = *(const float4*)(p + 4);
      }
      x2f[mf][kc][0] = v0.x; x2f[mf][kc][1] = v0.y;
      x2f[mf][kc][2] = v0.z; x2f[mf][kc][3] = v0.w;
      x2f[mf][kc][4] = v1.x; x2f[mf][kc][5] = v1.y;
      x2f[mf][kc][6] = v1.z; x2f[mf][kc][7] = v1.w;
    }
  }

  f32x4 acc[2][NF_];
#pragma unroll
  for (int mf = 0; mf < 2; ++mf)
#pragma unroll
    for (int nf = 0; nf < NF_; ++nf)
      acc[mf][nf] = (f32x4){0.f, 0.f, 0.f, 0.f};

  uint4 st[7];
  {
    const uint4* gs = Wfrag + (size_t)(n * 64 + 0) * 896;
#pragma unroll
    for (int r = 0; r < 7; ++r) st[r] = gs[tid + r * 128];
#pragma unroll
    for (int r = 0; r < 7; ++r) Wl[0][tid + r * 128] = st[r];
  }
  __syncthreads();

  for (int b = 0; b < 64; ++b) {
    int cur = b & 1, nxt = cur ^ 1;
    if (b + 1 < 64) {
      const uint4* gs = Wfrag + (size_t)(n * 64 + b + 1) * 896;
#pragma unroll
      for (int r = 0; r < 7; ++r) st[r] = gs[tid + r * 128];
    }
    bf16x8 afr[2][2];
#pragma unroll
    for (int mf = 0; mf < 2; ++mf) {
      float x1v = bf2f(x1s[b][wave * 32 + mf * 16 + (lane & 15)]);
#pragma unroll
      for (int kc = 0; kc < 2; ++kc)
#pragma unroll
        for (int j = 0; j < 8; ++j)
          afr[mf][kc][j] = (__bf16)(x1v * x2f[mf][kc][j]);
    }
#pragma unroll
    for (int nf = 0; nf < NF_; ++nf) {
#pragma unroll
      for (int kc = 0; kc < 2; ++kc) {
        bf16x8 bfr = *(const bf16x8*)&Wl[cur][(nf * 2 + kc) * 64 + lane];
#pragma unroll
        for (int mf = 0; mf < 2; ++mf)
          acc[mf][nf] = __builtin_amdgcn_mfma_f32_16x16x32_bf16(
              afr[mf][kc], bfr, acc[mf][nf], 0, 0, 0);
      }
    }
    if (b + 1 < 64) {
#pragma unroll
      for (int r = 0; r < 7; ++r) Wl[nxt][tid + r * 128] = st[r];
    }
    __syncthreads();
  }

#pragma unroll
  for (int mf = 0; mf < 2; ++mf) {
#pragma unroll
    for (int nf = 0; nf < NF_; ++nf) {
      int r = nf * 16 + (lane & 15);
      if (r < R_) {
#pragma unroll
        for (int reg = 0; reg < 4; ++reg) {
          int l = l0 + wave * 32 + mf * 16 + ((lane >> 4) << 2) + reg;
          if (l < L_)
            part[((size_t)n * L_ + l) * R_ + r] = acc[mf][nf][reg];
        }
      }
    }
  }
}

// ---------------------------------------------------------------------------
// K6: reduce partials over n, add clsb.
// ---------------------------------------------------------------------------
__global__ void reduce_logits(const float* __restrict__ part, const float* __restrict__ clsb,
                              float* __restrict__ out) {
  int idx = blockIdx.x * 256 + threadIdx.x;
  if (idx < L_ * R_) {
    int r = idx % R_;
    float s = clsb[r];
#pragma unroll
    for (int nn = 0; nn < NB_; ++nn) s += part[(size_t)nn * L_ * R_ + idx];
    out[idx] = s;
  }
}

extern "C" void kernel_launch(void* const* d_in, const int* in_sizes, int n_in,
                              void* d_out, int out_size, void* d_ws, size_t ws_size,
                              hipStream_t stream) {
  const float* hs   = (const float*)d_in[0];
  const float* attn = (const float*)d_in[1];
  const float* mask = (const float*)d_in[2];
  const int*   head = (const int*)d_in[3];
  const int*   tail = (const int*)d_in[4];
  const int*   etyp = (const int*)d_in[5];
  const float* ttab = (const float*)d_in[6];
  const float* dtab = (const float*)d_in[7];
  const float* Wh   = (const float*)d_in[8];
  const float* bh   = (const float*)d_in[9];
  const float* Wt   = (const float*)d_in[10];
  const float* bt   = (const float*)d_in[11];
  const float* clsW = (const float*)d_in[12];
  const float* clsb = (const float*)d_in[13];
  float* out = (float*)d_out;

  float* ws = (float*)d_ws;
  float* ent_att  = ws; ws += (size_t)B_ * E_ * S_;     // 49152 f
  float* ent_feat = ws; ws += (size_t)B_ * E_ * H_;     // 73728 f
  float* ht_att   = ws; ws += (size_t)L_ * S_;          // 1130496 f (4.52 MB)
  float* ht_info  = ws; ws += (size_t)L_ * H_;          // 1695744 f (6.78 MB)
  float* h1       = ws; ws += (size_t)L_ * H_;
  float* t1       = ws; ws += (size_t)L_ * H_;
  float* part     = ws; ws += (size_t)NB_ * L_ * R_;    // 2570112 f (10.28 MB)
  int* meta = (int*)ws;                                 // 5*L ints

  // Aliases (lifetime-disjoint):
  //  Wpack_h (2.36 MB)  in ht_att region   [alive: after htinfo_mfma .. mlp_mfma]
  //  Wpack_t (2.36 MB)  in part  region    [alive: .. mlp_mfma; part written later]
  //  hsPack  (3.00 MB)  in part +4MB       [alive: pack_hs .. htinfo_mfma]
  //  Wfrag   (11.0 MB)  in ht_att+ht_info  [alive: pack_w .. bilinear_mfma]
  uint4* Wpack_h = (uint4*)ht_att;
  uint4* Wpack_t = (uint4*)part;
  uint4* hsPack  = (uint4*)(part + (size_t)1048576);
  uint4* Wfrag   = (uint4*)ht_att;

  ent_prep<<<B_ * E_, 256, 0, stream>>>(attn, hs, head, tail, ent_att, ent_feat);
  pair_att<<<L_, 256, 0, stream>>>(ent_att, mask, head, tail, etyp, ht_att, meta);
  pack_hs<<<(B_ * KS_HTI * 48 * 64) / 256, 256, 0, stream>>>(hs, hsPack);
  htinfo_mfma<<<dim3(9, 6, B_), 256, 0, stream>>>(ht_att, hsPack, ht_info);
  pack_Wmlp<<<(KS_MLP * 48 * 64) / 256, 256, 0, stream>>>(Wh, Wpack_h);
  pack_Wmlp<<<(KS_MLP * 48 * 64) / 256, 256, 0, stream>>>(Wt, Wpack_t);
  mlp_mfma<<<dim3(35, 6, 2), 256, 0, stream>>>(ent_feat, ht_info, ttab, dtab, meta,
      Wpack_h, Wpack_t, bh, bt, h1, t1);
  pack_w<<<NB_ * 64, 256, 0, stream>>>(clsW, Wfrag);
  bilinear_mfma<<<dim3(35, NB_), 128, 0, stream>>>(h1, t1, Wfrag, part);
  reduce_logits<<<(L_ * R_ + 255) / 256, 256, 0, stream>>>(part, clsb, out);
}

// Round 4
// 143.503 us; speedup vs baseline: 10.0577x; 1.2429x over previous
//
#include <hip/hip_runtime.h>
#include <hip/hip_bf16.h>
#include <math.h>

#define B_ 4
#define S_ 512
#define H_ 768
#define NH_ 12
#define E_ 24
#define TE_ 20
#define TD_ 20
#define R_ 97
#define DIN_ 1576   // 2*H + TE + TD
#define KPAD_ 1600  // DIN padded to multiple of 32
#define KS_MLP 50   // KPAD/32
#define KS_HTI 16   // 512/32
#define P_ 552      // E*(E-1)
#define L_ 2208     // B*P
#define NB_ 12      // H/64
#define NF_ 7       // n-frags of 16 cols covering 97 -> 112

typedef __bf16 bf16x8 __attribute__((ext_vector_type(8)));
typedef float f32x4 __attribute__((ext_vector_type(4)));

__device__ __forceinline__ unsigned short f2bf(float f) {
  union { float f; unsigned u; } c; c.f = f;
  unsigned r = c.u + 0x7FFF + ((c.u >> 16) & 1);
  return (unsigned short)(r >> 16);
}
__device__ __forceinline__ float bf2f(unsigned short b) {
  union { unsigned u; float f; } c; c.u = ((unsigned)b) << 16;
  return c.f;
}
__device__ __forceinline__ unsigned pk2(float a, float b) {
  return (unsigned)f2bf(a) | ((unsigned)f2bf(b) << 16);
}
// async global->LDS, 16B per lane; LDS dest = wave-uniform base + lane*16
__device__ __forceinline__ void gload_lds16(const uint4* g, uint4* l) {
  __builtin_amdgcn_global_load_lds(
      (const __attribute__((address_space(1))) unsigned*)(const void*)g,
      (__attribute__((address_space(3))) unsigned*)(void*)l, 16, 0, 0);
}

// ---------------------------------------------------------------------------
// K1: per-entity gathered attention-row sum over heads + entity features.
// ---------------------------------------------------------------------------
__global__ void ent_prep(const float* __restrict__ attn, const float* __restrict__ hs,
                         const int* __restrict__ head, const int* __restrict__ tail,
                         float* __restrict__ ent_att, float* __restrict__ ent_feat) {
  int be = blockIdx.x;
  int b = be / E_;
  int hd = head[be], tl = tail[be];
  int tid = threadIdx.x;
  const float* abase = attn + (size_t)b * NH_ * S_ * S_;
  for (int s = tid; s < S_; s += 256) {
    float acc = 0.f;
#pragma unroll
    for (int nh = 0; nh < NH_; ++nh) {
      const float* ap = abase + (size_t)nh * S_ * S_;
      acc += ap[(size_t)hd * S_ + s] + ap[(size_t)tl * S_ + s];
    }
    ent_att[(size_t)be * S_ + s] = 0.5f * acc;
  }
  const float* hb = hs + (size_t)b * S_ * H_;
  for (int k = tid; k < H_; k += 256) {
    ent_feat[(size_t)be * H_ + k] = 0.5f * (hb[(size_t)hd * H_ + k] + hb[(size_t)tl * H_ + k]);
  }
}

// ---------------------------------------------------------------------------
// K2: pairwise attention product + mask + normalize; pair metadata.
// ---------------------------------------------------------------------------
__global__ void pair_att(const float* __restrict__ ent_att, const float* __restrict__ mask,
                         const int* __restrict__ head, const int* __restrict__ tail,
                         const int* __restrict__ etype,
                         float* __restrict__ ht_att, int* __restrict__ meta) {
  int l = blockIdx.x;
  int b = l / P_, p = l % P_;
  int i0 = p / (E_ - 1), rem = p % (E_ - 1);
  int i1 = rem + (rem >= i0 ? 1 : 0);
  int tid = threadIdx.x;
  if (tid == 0) {
    meta[0 * L_ + l] = b * E_ + i0;
    meta[1 * L_ + l] = b * E_ + i1;
    meta[2 * L_ + l] = etype[b * E_ + i0];
    meta[3 * L_ + l] = etype[b * E_ + i1];
    int d = abs(tail[b * E_ + i0] - head[b * E_ + i1]);
    int bk = (d >= 2) + (d >= 4) + (d >= 8) + (d >= 16) + (d >= 32) +
             (d >= 64) + (d >= 128) + (d >= 256) + (d >= 512);
    meta[4 * L_ + l] = bk;
  }
  const float* a0 = ent_att + (size_t)(b * E_ + i0) * S_;
  const float* a1 = ent_att + (size_t)(b * E_ + i1) * S_;
  const float* m = mask + (size_t)b * S_;
  float v0 = a0[tid] * a1[tid] * m[tid];
  float v1 = a0[tid + 256] * a1[tid + 256] * m[tid + 256];
  float loc = v0 + v1;
  for (int o = 32; o > 0; o >>= 1) loc += __shfl_down(loc, o, 64);
  __shared__ float red[4];
  if ((tid & 63) == 0) red[tid >> 6] = loc;
  __syncthreads();
  float tot = red[0] + red[1] + red[2] + red[3];
  float inv = 1.f / (tot + 1e-20f);
  ht_att[(size_t)l * S_ + tid] = v0 * inv;
  ht_att[(size_t)l * S_ + tid + 256] = v1 * inv;
}

// ---------------------------------------------------------------------------
// pack_hs: hs (B,S,H f32) -> bf16 fragment-major [b][ks][nt16][lane][8]
// ---------------------------------------------------------------------------
__global__ void pack_hs(const float* __restrict__ hs, uint4* __restrict__ hsP) {
  int u = blockIdx.x * 256 + threadIdx.x;
  if (u >= B_ * KS_HTI * 48 * 64) return;
  int lane = u & 63;
  int t = u >> 6;
  int nt16 = t % 48;
  int t2 = t / 48;
  int ks = t2 % KS_HTI;
  int b = t2 / KS_HTI;
  int n = nt16 * 16 + (lane & 15);
  int k0 = ks * 32 + ((lane >> 4) << 3);
  const float* src = hs + (size_t)b * S_ * H_;
  unsigned w[4];
#pragma unroll
  for (int q = 0; q < 4; ++q) {
    int k = k0 + 2 * q;
    w[q] = pk2(src[(size_t)k * H_ + n], src[(size_t)(k + 1) * H_ + n]);
  }
  uint4 o; o.x = w[0]; o.y = w[1]; o.z = w[2]; o.w = w[3];
  hsP[u] = o;
}

// ---------------------------------------------------------------------------
// pack_Wmlp: Wh/Wt (DIN,H f32) -> bf16 fragment-major [ks][nt16][lane][8]
// blockIdx.y selects which weight matrix.
// ---------------------------------------------------------------------------
__global__ void pack_Wmlp(const float* __restrict__ Wh, const float* __restrict__ Wt,
                          uint4* __restrict__ WpH, uint4* __restrict__ WpT) {
  int u = blockIdx.x * 256 + threadIdx.x;
  if (u >= KS_MLP * 48 * 64) return;
  const float* W = blockIdx.y ? Wt : Wh;
  uint4* Wp = blockIdx.y ? WpT : WpH;
  int lane = u & 63;
  int t = u >> 6;
  int nt16 = t % 48;
  int ks = t / 48;
  int n = nt16 * 16 + (lane & 15);
  int k0 = ks * 32 + ((lane >> 4) << 3);
  unsigned w[4];
#pragma unroll
  for (int q = 0; q < 4; ++q) {
    int k = k0 + 2 * q;
    float v0 = (k < DIN_) ? W[(size_t)k * H_ + n] : 0.f;
    float v1 = (k + 1 < DIN_) ? W[(size_t)(k + 1) * H_ + n] : 0.f;
    w[q] = pk2(v0, v1);
  }
  uint4 o; o.x = w[0]; o.y = w[1]; o.z = w[2]; o.w = w[3];
  Wp[u] = o;
}

// ---------------------------------------------------------------------------
// htinfo_mfma: ht_info = ht_att @ hs[b], bf16 MFMA (as R3).
// ---------------------------------------------------------------------------
__global__ __launch_bounds__(256) void htinfo_mfma(
    const float* __restrict__ htatt, const uint4* __restrict__ hsP,
    float* __restrict__ htinfo) {
  int b = blockIdx.z;
  int m0 = blockIdx.x * 64;
  int n0 = blockIdx.y * 128;
  int tid = threadIdx.x;
  int wave = tid >> 6, lane = tid & 63;
  int wm = wave & 1, wn = wave >> 1;
  __shared__ __align__(16) unsigned short Ash[2][2048];
  __shared__ __align__(16) unsigned short Bsh[2][4096];

  int amt = tid >> 6, alane = tid & 63;
  int arow = m0 + amt * 16 + (alane & 15);
  bool rowok = arow < P_;
  const float* ap = htatt + ((size_t)b * P_ + (rowok ? arow : 0)) * S_;
  int akoff = (alane >> 4) << 3;
  int nt0 = n0 >> 4;

  f32x4 acc[2][4];
#pragma unroll
  for (int i = 0; i < 2; ++i)
#pragma unroll
    for (int j = 0; j < 4; ++j) acc[i][j] = (f32x4){0.f, 0.f, 0.f, 0.f};

  {
    uint4 aU; size_t gb = ((size_t)(b * KS_HTI + 0) * 48 + nt0) * 64;
    uint4 b0 = hsP[gb + tid], b1 = hsP[gb + 256 + tid];
    if (rowok) {
      float4 v0 = *(const float4*)(ap + akoff);
      float4 v1 = *(const float4*)(ap + akoff + 4);
      aU.x = pk2(v0.x, v0.y); aU.y = pk2(v0.z, v0.w);
      aU.z = pk2(v1.x, v1.y); aU.w = pk2(v1.z, v1.w);
    } else aU.x = aU.y = aU.z = aU.w = 0;
    *(uint4*)&Ash[0][tid * 8] = aU;
    *(uint4*)&Bsh[0][tid * 8] = b0;
    *(uint4*)&Bsh[0][tid * 8 + 2048] = b1;
  }
  __syncthreads();

  for (int ks = 0; ks < KS_HTI; ++ks) {
    int cur = ks & 1, nxt = cur ^ 1;
    bool more = (ks + 1 < KS_HTI);
    uint4 aN, bN0, bN1;
    if (more) {
      size_t gb = ((size_t)(b * KS_HTI + ks + 1) * 48 + nt0) * 64;
      bN0 = hsP[gb + tid]; bN1 = hsP[gb + 256 + tid];
      int k = (ks + 1) * 32 + akoff;
      if (rowok) {
        float4 v0 = *(const float4*)(ap + k);
        float4 v1 = *(const float4*)(ap + k + 4);
        aN.x = pk2(v0.x, v0.y); aN.y = pk2(v0.z, v0.w);
        aN.z = pk2(v1.x, v1.y); aN.w = pk2(v1.z, v1.w);
      } else aN.x = aN.y = aN.z = aN.w = 0;
    }
    bf16x8 af[2], bf[4];
#pragma unroll
    for (int mf = 0; mf < 2; ++mf)
      af[mf] = *(const bf16x8*)&Ash[cur][((wm * 2 + mf) * 64 + lane) * 8];
#pragma unroll
    for (int nf = 0; nf < 4; ++nf)
      bf[nf] = *(const bf16x8*)&Bsh[cur][((wn * 4 + nf) * 64 + lane) * 8];
#pragma unroll
    for (int nf = 0; nf < 4; ++nf)
#pragma unroll
      for (int mf = 0; mf < 2; ++mf)
        acc[mf][nf] = __builtin_amdgcn_mfma_f32_16x16x32_bf16(af[mf], bf[nf], acc[mf][nf], 0, 0, 0);
    if (more) {
      *(uint4*)&Ash[nxt][tid * 8] = aN;
      *(uint4*)&Bsh[nxt][tid * 8] = bN0;
      *(uint4*)&Bsh[nxt][tid * 8 + 2048] = bN1;
    }
    __syncthreads();
  }

#pragma unroll
  for (int mf = 0; mf < 2; ++mf)
#pragma unroll
    for (int nf = 0; nf < 4; ++nf) {
      int n = n0 + (wn * 4 + nf) * 16 + (lane & 15);
#pragma unroll
      for (int reg = 0; reg < 4; ++reg) {
        int l = m0 + (wm * 2 + mf) * 16 + ((lane >> 4) << 2) + reg;
        if (l < P_)
          htinfo[((size_t)b * P_ + l) * H_ + n] = acc[mf][nf][reg];
      }
    }
}

// ---------------------------------------------------------------------------
// mlp_mfma: h1/t1 = tanh(all_x @ W + b) (as R3).
// ---------------------------------------------------------------------------
__global__ __launch_bounds__(256) void mlp_mfma(
    const float* __restrict__ ent_feat, const float* __restrict__ ht_info,
    const float* __restrict__ ttab, const float* __restrict__ dtab,
    const int* __restrict__ meta,
    const uint4* __restrict__ Wp_h, const uint4* __restrict__ Wp_t,
    const float* __restrict__ bh, const float* __restrict__ bt,
    float* __restrict__ h1, float* __restrict__ t1) {
  int half = blockIdx.z;
  const uint4* Wp = half ? Wp_t : Wp_h;
  const float* bias = half ? bt : bh;
  float* out = half ? t1 : h1;
  const int* feat_row = meta + half * L_;
  const int* type_row = meta + (2 + half) * L_;
  const int* distb = meta + 4 * L_;

  int l0 = blockIdx.x * 64;
  int n0 = blockIdx.y * 128;
  int tid = threadIdx.x;
  int wave = tid >> 6, lane = tid & 63;
  int wm = wave & 1, wn = wave >> 1;
  __shared__ __align__(16) unsigned short Ash[2][2048];
  __shared__ __align__(16) unsigned short Bsh[2][4096];

  int amt = tid >> 6, alane = tid & 63;
  int arow = l0 + amt * 16 + (alane & 15);
  bool rowok = arow < L_;
  int frow = 0, trow = 0, db = 0;
  if (rowok) { frow = feat_row[arow]; trow = type_row[arow]; db = distb[arow]; }
  const float* efp = ent_feat + (size_t)frow * H_;
  const float* hip_ = ht_info + (size_t)arow * H_;
  int akoff = (alane >> 4) << 3;
  int nt0 = n0 >> 4;

  f32x4 acc[2][4];
#pragma unroll
  for (int i = 0; i < 2; ++i)
#pragma unroll
    for (int j = 0; j < 4; ++j) acc[i][j] = (f32x4){0.f, 0.f, 0.f, 0.f};

  auto gatherA = [&](int ks, uint4& d) {
    int k = ks * 32 + akoff;
    if (!rowok) { d.x = d.y = d.z = d.w = 0; return; }
    if (k < 768) {
      float4 v0 = *(const float4*)(efp + k);
      float4 v1 = *(const float4*)(efp + k + 4);
      d.x = pk2(v0.x, v0.y); d.y = pk2(v0.z, v0.w);
      d.z = pk2(v1.x, v1.y); d.w = pk2(v1.z, v1.w);
    } else if (k < 1536) {
      float4 v0 = *(const float4*)(hip_ + k - 768);
      float4 v1 = *(const float4*)(hip_ + k - 764);
      d.x = pk2(v0.x, v0.y); d.y = pk2(v0.z, v0.w);
      d.z = pk2(v1.x, v1.y); d.w = pk2(v1.z, v1.w);
    } else {
      float v[8];
#pragma unroll
      for (int j = 0; j < 8; ++j) {
        int e = k + j;
        v[j] = (e < 1556) ? ttab[trow * TE_ + (e - 1536)]
             : (e < 1576) ? dtab[db * TD_ + (e - 1556)] : 0.f;
      }
      d.x = pk2(v[0], v[1]); d.y = pk2(v[2], v[3]);
      d.z = pk2(v[4], v[5]); d.w = pk2(v[6], v[7]);
    }
  };

  {
    uint4 aU; gatherA(0, aU);
    size_t gb = ((size_t)0 * 48 + nt0) * 64;
    uint4 b0 = Wp[gb + tid], b1 = Wp[gb + 256 + tid];
    *(uint4*)&Ash[0][tid * 8] = aU;
    *(uint4*)&Bsh[0][tid * 8] = b0;
    *(uint4*)&Bsh[0][tid * 8 + 2048] = b1;
  }
  __syncthreads();

  for (int ks = 0; ks < KS_MLP; ++ks) {
    int cur = ks & 1, nxt = cur ^ 1;
    bool more = (ks + 1 < KS_MLP);
    uint4 aN, bN0, bN1;
    if (more) {
      size_t gb = ((size_t)(ks + 1) * 48 + nt0) * 64;
      bN0 = Wp[gb + tid]; bN1 = Wp[gb + 256 + tid];
      gatherA(ks + 1, aN);
    }
    bf16x8 af[2], bf[4];
#pragma unroll
    for (int mf = 0; mf < 2; ++mf)
      af[mf] = *(const bf16x8*)&Ash[cur][((wm * 2 + mf) * 64 + lane) * 8];
#pragma unroll
    for (int nf = 0; nf < 4; ++nf)
      bf[nf] = *(const bf16x8*)&Bsh[cur][((wn * 4 + nf) * 64 + lane) * 8];
#pragma unroll
    for (int nf = 0; nf < 4; ++nf)
#pragma unroll
      for (int mf = 0; mf < 2; ++mf)
        acc[mf][nf] = __builtin_amdgcn_mfma_f32_16x16x32_bf16(af[mf], bf[nf], acc[mf][nf], 0, 0, 0);
    if (more) {
      *(uint4*)&Ash[nxt][tid * 8] = aN;
      *(uint4*)&Bsh[nxt][tid * 8] = bN0;
      *(uint4*)&Bsh[nxt][tid * 8 + 2048] = bN1;
    }
    __syncthreads();
  }

#pragma unroll
  for (int mf = 0; mf < 2; ++mf)
#pragma unroll
    for (int nf = 0; nf < 4; ++nf) {
      int n = n0 + (wn * 4 + nf) * 16 + (lane & 15);
      float bv = bias[n];
#pragma unroll
      for (int reg = 0; reg < 4; ++reg) {
        int l = l0 + (wm * 2 + mf) * 16 + ((lane >> 4) << 2) + reg;
        if (l < L_)
          out[(size_t)l * H_ + n] = tanhf(acc[mf][nf][reg] + bv);
      }
    }
}

// ---------------------------------------------------------------------------
// K5a: pre-pack clsW -> fragment-major bf16 for the bilinear B-operand.
// ---------------------------------------------------------------------------
__global__ void pack_w(const float* __restrict__ clsW, uint4* __restrict__ Wfrag) {
  int nb = blockIdx.x;            // n*64 + b
  __shared__ float Wls[64][98];
  int tid = threadIdx.x;
  const float* src = clsW + (size_t)nb * 64 * R_;
  for (int idx = tid; idx < 64 * R_; idx += 256) {
    Wls[idx / R_][idx % R_] = src[idx];
  }
  __syncthreads();
  for (int u = tid; u < 896; u += 256) {
    int nf = u >> 7;
    int kc = (u >> 6) & 1;
    int lane = u & 63;
    int r = (lane & 15) + 16 * nf;
    unsigned w[4];
#pragma unroll
    for (int q = 0; q < 4; ++q) {
      int c0 = ((lane >> 4) << 3) + 2 * q + 32 * kc;
      float v0 = (r < R_) ? Wls[c0][r] : 0.f;
      float v1 = (r < R_) ? Wls[c0 + 1][r] : 0.f;
      w[q] = (unsigned)f2bf(v0) | ((unsigned)f2bf(v1) << 16);
    }
    uint4 o; o.x = w[0]; o.y = w[1]; o.z = w[2]; o.w = w[3];
    Wfrag[(size_t)nb * 896 + u] = o;
  }
}

// ---------------------------------------------------------------------------
// K5b v2: bilinear MFMA. 4 waves: wm = wave&1 (m-half), kh = wave>>1 (K-half,
// 32 b's each). W staged via global_load_lds (linear LDS), double-buffered,
// one barrier per b-step. Cross-kh reduction in LDS at the end.
// LDS: Wl 57344 + x1s 8192 = 65536 B -> 2 blocks/CU.
// ---------------------------------------------------------------------------
__global__ __launch_bounds__(256) void bilinear_mfma(
    const float* __restrict__ h1, const float* __restrict__ t1,
    const uint4* __restrict__ Wfrag, float* __restrict__ part) {
  int n = blockIdx.y;
  int l0 = blockIdx.x * 64;
  int tid = threadIdx.x;
  int wave = tid >> 6, lane = tid & 63;
  int wm = wave & 1, kh = wave >> 1;
  __shared__ __align__(16) uint4 Wl[2][2][896];   // [kh][dbuf][unit]
  __shared__ unsigned short x1s[64][64];          // [b][l], bf16 bits

  // x1 tile -> LDS transposed (one-off; write conflicts acceptable)
  for (int i = tid; i < 1024; i += 256) {
    int l = i >> 4, bq = (i & 15) * 4;
    float4 v = make_float4(0, 0, 0, 0);
    if (l0 + l < L_) v = *(const float4*)(h1 + (size_t)(l0 + l) * H_ + n * 64 + bq);
    x1s[bq + 0][l] = f2bf(v.x);
    x1s[bq + 1][l] = f2bf(v.y);
    x1s[bq + 2][l] = f2bf(v.z);
    x1s[bq + 3][l] = f2bf(v.w);
  }

  // x2 fragments (loop-invariant per n), f32 regs
  float x2f[2][2][8];
#pragma unroll
  for (int mf = 0; mf < 2; ++mf) {
    int row = l0 + wm * 32 + mf * 16 + (lane & 15);
#pragma unroll
    for (int kc = 0; kc < 2; ++kc) {
      float4 v0 = make_float4(0, 0, 0, 0), v1 = v0;
      if (row < L_) {
        const float* p = t1 + (size_t)row * H_ + n * 64 + kc * 32 + ((lane >> 4) << 3);
        v0 = *(const float4*)p;
        v1 = *(const float4*)(p + 4);
      }
      x2f[mf][kc][0] = v0.x; x2f[mf][kc][1] = v0.y;
      x2f[mf][kc][2] = v0.z; x2f[mf][kc][3] = v0.w;
      x2f[mf][kc][4] = v1.x; x2f[mf][kc][5] = v1.y;
      x2f[mf][kc][6] = v1.z; x2f[mf][kc][7] = v1.w;
    }
  }

  f32x4 acc[2][NF_];
#pragma unroll
  for (int mf = 0; mf < 2; ++mf)
#pragma unroll
    for (int nf = 0; nf < NF_; ++nf)
      acc[mf][nf] = (f32x4){0.f, 0.f, 0.f, 0.f};

  const uint4* gbase = Wfrag + (size_t)n * 64 * 896;
  // stage b into Wl[kh][buf]: this kh-group's 2 waves cover 14 1KB chunks
  auto stage = [&](int b, int buf) {
    const uint4* gs = gbase + (size_t)b * 896 + (wm * 7) * 64 + lane;
#pragma unroll
    for (int r = 0; r < 7; ++r)
      gload_lds16(gs + r * 64, &Wl[kh][buf][(wm * 7 + r) * 64]);
  };

  stage(kh * 32, 0);
  __syncthreads();   // drains vmcnt -> buf0 + x1s ready

  for (int s = 0; s < 32; ++s) {
    int b = kh * 32 + s;
    int cur = s & 1, nxt = cur ^ 1;
    if (s + 1 < 32) stage(b + 1, nxt);
    // compose A-fragments for this b
    bf16x8 afr[2][2];
#pragma unroll
    for (int mf = 0; mf < 2; ++mf) {
      float x1v = bf2f(x1s[b][wm * 32 + mf * 16 + (lane & 15)]);
#pragma unroll
      for (int kc = 0; kc < 2; ++kc)
#pragma unroll
        for (int j = 0; j < 8; ++j)
          afr[mf][kc][j] = (__bf16)(x1v * x2f[mf][kc][j]);
    }
#pragma unroll
    for (int nf = 0; nf < NF_; ++nf) {
#pragma unroll
      for (int kc = 0; kc < 2; ++kc) {
        bf16x8 bfr = *(const bf16x8*)&Wl[kh][cur][(nf * 2 + kc) * 64 + lane];
#pragma unroll
        for (int mf = 0; mf < 2; ++mf)
          acc[mf][nf] = __builtin_amdgcn_mfma_f32_16x16x32_bf16(
              afr[mf][kc], bfr, acc[mf][nf], 0, 0, 0);
      }
    }
    __syncthreads();  // drains vmcnt -> nxt ready; guards cur reuse
  }

  // cross-kh reduction via LDS (reuse Wl area; stride 68 floats = 2-way banks)
  float* red = (float*)&Wl[0][0][0];
  int rbase = (wm * 64 + lane) * 68;
  if (kh == 1) {
#pragma unroll
    for (int mf = 0; mf < 2; ++mf)
#pragma unroll
      for (int nf = 0; nf < NF_; ++nf)
        *(f32x4*)&red[rbase + (mf * NF_ + nf) * 4] = acc[mf][nf];
  }
  __syncthreads();
  if (kh == 0) {
#pragma unroll
    for (int mf = 0; mf < 2; ++mf)
#pragma unroll
      for (int nf = 0; nf < NF_; ++nf)
        acc[mf][nf] += *(const f32x4*)&red[rbase + (mf * NF_ + nf) * 4];
#pragma unroll
    for (int mf = 0; mf < 2; ++mf) {
#pragma unroll
      for (int nf = 0; nf < NF_; ++nf) {
        int r = nf * 16 + (lane & 15);
        if (r < R_) {
#pragma unroll
          for (int reg = 0; reg < 4; ++reg) {
            int l = l0 + wm * 32 + mf * 16 + ((lane >> 4) << 2) + reg;
            if (l < L_)
              part[((size_t)n * L_ + l) * R_ + r] = acc[mf][nf][reg];
          }
        }
      }
    }
  }
}

// ---------------------------------------------------------------------------
// K6: reduce partials over n, add clsb.
// ---------------------------------------------------------------------------
__global__ void reduce_logits(const float* __restrict__ part, const float* __restrict__ clsb,
                              float* __restrict__ out) {
  int idx = blockIdx.x * 256 + threadIdx.x;
  if (idx < L_ * R_) {
    int r = idx % R_;
    float s = clsb[r];
#pragma unroll
    for (int nn = 0; nn < NB_; ++nn) s += part[(size_t)nn * L_ * R_ + idx];
    out[idx] = s;
  }
}

extern "C" void kernel_launch(void* const* d_in, const int* in_sizes, int n_in,
                              void* d_out, int out_size, void* d_ws, size_t ws_size,
                              hipStream_t stream) {
  const float* hs   = (const float*)d_in[0];
  const float* attn = (const float*)d_in[1];
  const float* mask = (const float*)d_in[2];
  const int*   head = (const int*)d_in[3];
  const int*   tail = (const int*)d_in[4];
  const int*   etyp = (const int*)d_in[5];
  const float* ttab = (const float*)d_in[6];
  const float* dtab = (const float*)d_in[7];
  const float* Wh   = (const float*)d_in[8];
  const float* bh   = (const float*)d_in[9];
  const float* Wt   = (const float*)d_in[10];
  const float* bt   = (const float*)d_in[11];
  const float* clsW = (const float*)d_in[12];
  const float* clsb = (const float*)d_in[13];
  float* out = (float*)d_out;

  float* ws = (float*)d_ws;
  float* ent_att  = ws; ws += (size_t)B_ * E_ * S_;
  float* ent_feat = ws; ws += (size_t)B_ * E_ * H_;
  float* ht_att   = ws; ws += (size_t)L_ * S_;
  float* ht_info  = ws; ws += (size_t)L_ * H_;
  float* h1       = ws; ws += (size_t)L_ * H_;
  float* t1       = ws; ws += (size_t)L_ * H_;
  float* part     = ws; ws += (size_t)NB_ * L_ * R_;
  int* meta = (int*)ws;

  uint4* Wpack_h = (uint4*)ht_att;
  uint4* Wpack_t = (uint4*)part;
  uint4* hsPack  = (uint4*)(part + (size_t)1048576);
  uint4* Wfrag   = (uint4*)ht_att;

  ent_prep<<<B_ * E_, 256, 0, stream>>>(attn, hs, head, tail, ent_att, ent_feat);
  pair_att<<<L_, 256, 0, stream>>>(ent_att, mask, head, tail, etyp, ht_att, meta);
  pack_hs<<<(B_ * KS_HTI * 48 * 64) / 256, 256, 0, stream>>>(hs, hsPack);
  htinfo_mfma<<<dim3(9, 6, B_), 256, 0, stream>>>(ht_att, hsPack, ht_info);
  pack_Wmlp<<<dim3((KS_MLP * 48 * 64) / 256, 2), 256, 0, stream>>>(Wh, Wt, Wpack_h, Wpack_t);
  mlp_mfma<<<dim3(35, 6, 2), 256, 0, stream>>>(ent_feat, ht_info, ttab, dtab, meta,
      Wpack_h, Wpack_t, bh, bt, h1, t1);
  pack_w<<<NB_ * 64, 256, 0, stream>>>(clsW, Wfrag);
  bilinear_mfma<<<dim3(35, NB_), 256, 0, stream>>>(h1, t1, Wfrag, part);
  reduce_logits<<<(L_ * R_ + 255) / 256, 256, 0, stream>>>(part, clsb, out);
}

// Round 5
// 141.929 us; speedup vs baseline: 10.1692x; 1.0111x over previous
//
#include <hip/hip_runtime.h>
#include <hip/hip_bf16.h>
#include <math.h>

#define B_ 4
#define S_ 512
#define H_ 768
#define NH_ 12
#define E_ 24
#define TE_ 20
#define TD_ 20
#define R_ 97
#define DIN_ 1576   // 2*H + TE + TD
#define KPAD_ 1600  // DIN padded to multiple of 32
#define KS_MLP 50   // KPAD/32
#define KS_HTI 16   // 512/32
#define P_ 552      // E*(E-1)
#define L_ 2208     // B*P
#define NB_ 12      // H/64
#define NF_ 7       // n-frags of 16 cols covering 97 -> 112

typedef __bf16 bf16x8 __attribute__((ext_vector_type(8)));
typedef float f32x4 __attribute__((ext_vector_type(4)));

__device__ __forceinline__ unsigned short f2bf(float f) {
  union { float f; unsigned u; } c; c.f = f;
  unsigned r = c.u + 0x7FFF + ((c.u >> 16) & 1);
  return (unsigned short)(r >> 16);
}
__device__ __forceinline__ float bf2f(unsigned short b) {
  union { unsigned u; float f; } c; c.u = ((unsigned)b) << 16;
  return c.f;
}
__device__ __forceinline__ unsigned pk2(float a, float b) {
  return (unsigned)f2bf(a) | ((unsigned)f2bf(b) << 16);
}
// async global->LDS, 16B per lane; LDS dest = wave-uniform base + lane*16
__device__ __forceinline__ void gload_lds16(const uint4* g, uint4* l) {
  __builtin_amdgcn_global_load_lds(
      (const __attribute__((address_space(1))) unsigned*)(const void*)g,
      (__attribute__((address_space(3))) unsigned*)(void*)l, 16, 0, 0);
}

// ---------------------------------------------------------------------------
// K1: per-entity gathered attention-row sum over heads + entity features.
// ---------------------------------------------------------------------------
__global__ void ent_prep(const float* __restrict__ attn, const float* __restrict__ hs,
                         const int* __restrict__ head, const int* __restrict__ tail,
                         float* __restrict__ ent_att, float* __restrict__ ent_feat) {
  int be = blockIdx.x;
  int b = be / E_;
  int hd = head[be], tl = tail[be];
  int tid = threadIdx.x;
  const float* abase = attn + (size_t)b * NH_ * S_ * S_;
  for (int s = tid; s < S_; s += 256) {
    float acc = 0.f;
#pragma unroll
    for (int nh = 0; nh < NH_; ++nh) {
      const float* ap = abase + (size_t)nh * S_ * S_;
      acc += ap[(size_t)hd * S_ + s] + ap[(size_t)tl * S_ + s];
    }
    ent_att[(size_t)be * S_ + s] = 0.5f * acc;
  }
  const float* hb = hs + (size_t)b * S_ * H_;
  for (int k = tid; k < H_; k += 256) {
    ent_feat[(size_t)be * H_ + k] = 0.5f * (hb[(size_t)hd * H_ + k] + hb[(size_t)tl * H_ + k]);
  }
}

// ---------------------------------------------------------------------------
// K2: pairwise attention product + mask + normalize; pair metadata.
// ---------------------------------------------------------------------------
__global__ void pair_att(const float* __restrict__ ent_att, const float* __restrict__ mask,
                         const int* __restrict__ head, const int* __restrict__ tail,
                         const int* __restrict__ etype,
                         float* __restrict__ ht_att, int* __restrict__ meta) {
  int l = blockIdx.x;
  int b = l / P_, p = l % P_;
  int i0 = p / (E_ - 1), rem = p % (E_ - 1);
  int i1 = rem + (rem >= i0 ? 1 : 0);
  int tid = threadIdx.x;
  if (tid == 0) {
    meta[0 * L_ + l] = b * E_ + i0;
    meta[1 * L_ + l] = b * E_ + i1;
    meta[2 * L_ + l] = etype[b * E_ + i0];
    meta[3 * L_ + l] = etype[b * E_ + i1];
    int d = abs(tail[b * E_ + i0] - head[b * E_ + i1]);
    int bk = (d >= 2) + (d >= 4) + (d >= 8) + (d >= 16) + (d >= 32) +
             (d >= 64) + (d >= 128) + (d >= 256) + (d >= 512);
    meta[4 * L_ + l] = bk;
  }
  const float* a0 = ent_att + (size_t)(b * E_ + i0) * S_;
  const float* a1 = ent_att + (size_t)(b * E_ + i1) * S_;
  const float* m = mask + (size_t)b * S_;
  float v0 = a0[tid] * a1[tid] * m[tid];
  float v1 = a0[tid + 256] * a1[tid + 256] * m[tid + 256];
  float loc = v0 + v1;
  for (int o = 32; o > 0; o >>= 1) loc += __shfl_down(loc, o, 64);
  __shared__ float red[4];
  if ((tid & 63) == 0) red[tid >> 6] = loc;
  __syncthreads();
  float tot = red[0] + red[1] + red[2] + red[3];
  float inv = 1.f / (tot + 1e-20f);
  ht_att[(size_t)l * S_ + tid] = v0 * inv;
  ht_att[(size_t)l * S_ + tid + 256] = v1 * inv;
}

// ---------------------------------------------------------------------------
// pack_hs: hs (B,S,H f32) -> bf16 fragment-major [b][ks][nt16][lane][8]
// ---------------------------------------------------------------------------
__global__ void pack_hs(const float* __restrict__ hs, uint4* __restrict__ hsP) {
  int u = blockIdx.x * 256 + threadIdx.x;
  if (u >= B_ * KS_HTI * 48 * 64) return;
  int lane = u & 63;
  int t = u >> 6;
  int nt16 = t % 48;
  int t2 = t / 48;
  int ks = t2 % KS_HTI;
  int b = t2 / KS_HTI;
  int n = nt16 * 16 + (lane & 15);
  int k0 = ks * 32 + ((lane >> 4) << 3);
  const float* src = hs + (size_t)b * S_ * H_;
  unsigned w[4];
#pragma unroll
  for (int q = 0; q < 4; ++q) {
    int k = k0 + 2 * q;
    w[q] = pk2(src[(size_t)k * H_ + n], src[(size_t)(k + 1) * H_ + n]);
  }
  uint4 o; o.x = w[0]; o.y = w[1]; o.z = w[2]; o.w = w[3];
  hsP[u] = o;
}

// ---------------------------------------------------------------------------
// pack_Wmlp: Wh/Wt (DIN,H f32) -> bf16 fragment-major [ks][nt16][lane][8]
// ---------------------------------------------------------------------------
__global__ void pack_Wmlp(const float* __restrict__ Wh, const float* __restrict__ Wt,
                          uint4* __restrict__ WpH, uint4* __restrict__ WpT) {
  int u = blockIdx.x * 256 + threadIdx.x;
  if (u >= KS_MLP * 48 * 64) return;
  const float* W = blockIdx.y ? Wt : Wh;
  uint4* Wp = blockIdx.y ? WpT : WpH;
  int lane = u & 63;
  int t = u >> 6;
  int nt16 = t % 48;
  int ks = t / 48;
  int n = nt16 * 16 + (lane & 15);
  int k0 = ks * 32 + ((lane >> 4) << 3);
  unsigned w[4];
#pragma unroll
  for (int q = 0; q < 4; ++q) {
    int k = k0 + 2 * q;
    float v0 = (k < DIN_) ? W[(size_t)k * H_ + n] : 0.f;
    float v1 = (k + 1 < DIN_) ? W[(size_t)(k + 1) * H_ + n] : 0.f;
    w[q] = pk2(v0, v1);
  }
  uint4 o; o.x = w[0]; o.y = w[1]; o.z = w[2]; o.w = w[3];
  Wp[u] = o;
}

// ---------------------------------------------------------------------------
// htinfo_mfma v2: BM=64 BN=64, 4 waves (2m x 2n), grid (9,12,B_)=432 blocks.
// B staged via global_load_lds (1KB chunk per wave per step); A reg-staged.
// ---------------------------------------------------------------------------
__global__ __launch_bounds__(256) void htinfo_mfma(
    const float* __restrict__ htatt, const uint4* __restrict__ hsP,
    float* __restrict__ htinfo) {
  int b = blockIdx.z;
  int m0 = blockIdx.x * 64;
  int n0 = blockIdx.y * 64;
  int tid = threadIdx.x;
  int wave = tid >> 6, lane = tid & 63;
  int wm = wave & 1, wn = wave >> 1;
  __shared__ __align__(16) unsigned short Ash[2][2048];
  __shared__ __align__(16) uint4 Bsh[2][256];   // 4 frags x 64 lanes

  int amt = tid >> 6, alane = tid & 63;
  int arow = m0 + amt * 16 + (alane & 15);
  bool rowok = arow < P_;
  const float* ap = htatt + ((size_t)b * P_ + (rowok ? arow : 0)) * S_;
  int akoff = (alane >> 4) << 3;
  int nt0 = n0 >> 4;

  f32x4 acc[2][2];
#pragma unroll
  for (int i = 0; i < 2; ++i)
#pragma unroll
    for (int j = 0; j < 2; ++j) acc[i][j] = (f32x4){0.f, 0.f, 0.f, 0.f};

  auto stageB = [&](int ks, int buf) {
    const uint4* gs = hsP + ((size_t)(b * KS_HTI + ks) * 48 + nt0 + wave) * 64 + lane;
    gload_lds16(gs, &Bsh[buf][wave * 64]);
  };
  auto gatherA = [&](int ks, uint4& d) {
    if (!rowok) { d.x = d.y = d.z = d.w = 0; return; }
    int k = ks * 32 + akoff;
    float4 v0 = *(const float4*)(ap + k);
    float4 v1 = *(const float4*)(ap + k + 4);
    d.x = pk2(v0.x, v0.y); d.y = pk2(v0.z, v0.w);
    d.z = pk2(v1.x, v1.y); d.w = pk2(v1.z, v1.w);
  };

  {
    stageB(0, 0);
    uint4 aU; gatherA(0, aU);
    *(uint4*)&Ash[0][tid * 8] = aU;
  }
  __syncthreads();

  for (int ks = 0; ks < KS_HTI; ++ks) {
    int cur = ks & 1, nxt = cur ^ 1;
    bool more = (ks + 1 < KS_HTI);
    uint4 aN;
    if (more) {
      stageB(ks + 1, nxt);
      gatherA(ks + 1, aN);
    }
    bf16x8 af[2], bf[2];
#pragma unroll
    for (int mf = 0; mf < 2; ++mf)
      af[mf] = *(const bf16x8*)&Ash[cur][((wm * 2 + mf) * 64 + lane) * 8];
#pragma unroll
    for (int nf = 0; nf < 2; ++nf)
      bf[nf] = *(const bf16x8*)&Bsh[cur][(wn * 2 + nf) * 64 + lane];
#pragma unroll
    for (int nf = 0; nf < 2; ++nf)
#pragma unroll
      for (int mf = 0; mf < 2; ++mf)
        acc[mf][nf] = __builtin_amdgcn_mfma_f32_16x16x32_bf16(af[mf], bf[nf], acc[mf][nf], 0, 0, 0);
    if (more)
      *(uint4*)&Ash[nxt][tid * 8] = aN;
    __syncthreads();
  }

#pragma unroll
  for (int mf = 0; mf < 2; ++mf)
#pragma unroll
    for (int nf = 0; nf < 2; ++nf) {
      int n = n0 + (wn * 2 + nf) * 16 + (lane & 15);
#pragma unroll
      for (int reg = 0; reg < 4; ++reg) {
        int l = m0 + (wm * 2 + mf) * 16 + ((lane >> 4) << 2) + reg;
        if (l < P_)
          htinfo[((size_t)b * P_ + l) * H_ + n] = acc[mf][nf][reg];
      }
    }
}

// ---------------------------------------------------------------------------
// mlp_mfma v2: BM=64 BN=64, 4 waves (2m x 2n), grid (35,12,2)=840 blocks.
// B (Wpack) staged via global_load_lds; A gathered+cvt in regs per K-step.
// ---------------------------------------------------------------------------
__global__ __launch_bounds__(256) void mlp_mfma(
    const float* __restrict__ ent_feat, const float* __restrict__ ht_info,
    const float* __restrict__ ttab, const float* __restrict__ dtab,
    const int* __restrict__ meta,
    const uint4* __restrict__ Wp_h, const uint4* __restrict__ Wp_t,
    const float* __restrict__ bh, const float* __restrict__ bt,
    float* __restrict__ h1, float* __restrict__ t1) {
  int half = blockIdx.z;
  const uint4* Wp = half ? Wp_t : Wp_h;
  const float* bias = half ? bt : bh;
  float* out = half ? t1 : h1;
  const int* feat_row = meta + half * L_;
  const int* type_row = meta + (2 + half) * L_;
  const int* distb = meta + 4 * L_;

  int l0 = blockIdx.x * 64;
  int n0 = blockIdx.y * 64;
  int tid = threadIdx.x;
  int wave = tid >> 6, lane = tid & 63;
  int wm = wave & 1, wn = wave >> 1;
  __shared__ __align__(16) unsigned short Ash[2][2048];
  __shared__ __align__(16) uint4 Bsh[2][256];

  int amt = tid >> 6, alane = tid & 63;
  int arow = l0 + amt * 16 + (alane & 15);
  bool rowok = arow < L_;
  int frow = 0, trow = 0, db = 0;
  if (rowok) { frow = feat_row[arow]; trow = type_row[arow]; db = distb[arow]; }
  const float* efp = ent_feat + (size_t)frow * H_;
  const float* hip_ = ht_info + (size_t)arow * H_;
  int akoff = (alane >> 4) << 3;
  int nt0 = n0 >> 4;

  f32x4 acc[2][2];
#pragma unroll
  for (int i = 0; i < 2; ++i)
#pragma unroll
    for (int j = 0; j < 2; ++j) acc[i][j] = (f32x4){0.f, 0.f, 0.f, 0.f};

  auto stageB = [&](int ks, int buf) {
    const uint4* gs = Wp + ((size_t)ks * 48 + nt0 + wave) * 64 + lane;
    gload_lds16(gs, &Bsh[buf][wave * 64]);
  };
  auto gatherA = [&](int ks, uint4& d) {
    int k = ks * 32 + akoff;
    if (!rowok) { d.x = d.y = d.z = d.w = 0; return; }
    if (k < 768) {
      float4 v0 = *(const float4*)(efp + k);
      float4 v1 = *(const float4*)(efp + k + 4);
      d.x = pk2(v0.x, v0.y); d.y = pk2(v0.z, v0.w);
      d.z = pk2(v1.x, v1.y); d.w = pk2(v1.z, v1.w);
    } else if (k < 1536) {
      float4 v0 = *(const float4*)(hip_ + k - 768);
      float4 v1 = *(const float4*)(hip_ + k - 764);
      d.x = pk2(v0.x, v0.y); d.y = pk2(v0.z, v0.w);
      d.z = pk2(v1.x, v1.y); d.w = pk2(v1.z, v1.w);
    } else {
      float v[8];
#pragma unroll
      for (int j = 0; j < 8; ++j) {
        int e = k + j;
        v[j] = (e < 1556) ? ttab[trow * TE_ + (e - 1536)]
             : (e < 1576) ? dtab[db * TD_ + (e - 1556)] : 0.f;
      }
      d.x = pk2(v[0], v[1]); d.y = pk2(v[2], v[3]);
      d.z = pk2(v[4], v[5]); d.w = pk2(v[6], v[7]);
    }
  };

  {
    stageB(0, 0);
    uint4 aU; gatherA(0, aU);
    *(uint4*)&Ash[0][tid * 8] = aU;
  }
  __syncthreads();

  for (int ks = 0; ks < KS_MLP; ++ks) {
    int cur = ks & 1, nxt = cur ^ 1;
    bool more = (ks + 1 < KS_MLP);
    uint4 aN;
    if (more) {
      stageB(ks + 1, nxt);
      gatherA(ks + 1, aN);
    }
    bf16x8 af[2], bf[2];
#pragma unroll
    for (int mf = 0; mf < 2; ++mf)
      af[mf] = *(const bf16x8*)&Ash[cur][((wm * 2 + mf) * 64 + lane) * 8];
#pragma unroll
    for (int nf = 0; nf < 2; ++nf)
      bf[nf] = *(const bf16x8*)&Bsh[cur][(wn * 2 + nf) * 64 + lane];
#pragma unroll
    for (int nf = 0; nf < 2; ++nf)
#pragma unroll
      for (int mf = 0; mf < 2; ++mf)
        acc[mf][nf] = __builtin_amdgcn_mfma_f32_16x16x32_bf16(af[mf], bf[nf], acc[mf][nf], 0, 0, 0);
    if (more)
      *(uint4*)&Ash[nxt][tid * 8] = aN;
    __syncthreads();
  }

#pragma unroll
  for (int mf = 0; mf < 2; ++mf)
#pragma unroll
    for (int nf = 0; nf < 2; ++nf) {
      int n = n0 + (wn * 2 + nf) * 16 + (lane & 15);
      float bv = bias[n];
#pragma unroll
      for (int reg = 0; reg < 4; ++reg) {
        int l = l0 + (wm * 2 + mf) * 16 + ((lane >> 4) << 2) + reg;
        if (l < L_)
          out[(size_t)l * H_ + n] = tanhf(acc[mf][nf][reg] + bv);
      }
    }
}

// ---------------------------------------------------------------------------
// K5a: pre-pack clsW -> fragment-major bf16 for the bilinear B-operand.
// ---------------------------------------------------------------------------
__global__ void pack_w(const float* __restrict__ clsW, uint4* __restrict__ Wfrag) {
  int nb = blockIdx.x;            // n*64 + b
  __shared__ float Wls[64][98];
  int tid = threadIdx.x;
  const float* src = clsW + (size_t)nb * 64 * R_;
  for (int idx = tid; idx < 64 * R_; idx += 256) {
    Wls[idx / R_][idx % R_] = src[idx];
  }
  __syncthreads();
  for (int u = tid; u < 896; u += 256) {
    int nf = u >> 7;
    int kc = (u >> 6) & 1;
    int lane = u & 63;
    int r = (lane & 15) + 16 * nf;
    unsigned w[4];
#pragma unroll
    for (int q = 0; q < 4; ++q) {
      int c0 = ((lane >> 4) << 3) + 2 * q + 32 * kc;
      float v0 = (r < R_) ? Wls[c0][r] : 0.f;
      float v1 = (r < R_) ? Wls[c0 + 1][r] : 0.f;
      w[q] = (unsigned)f2bf(v0) | ((unsigned)f2bf(v1) << 16);
    }
    uint4 o; o.x = w[0]; o.y = w[1]; o.z = w[2]; o.w = w[3];
    Wfrag[(size_t)nb * 896 + u] = o;
  }
}

// ---------------------------------------------------------------------------
// K5b: bilinear MFMA (as R4: 4 waves, wave-pair K-split, gload_lds W).
// ---------------------------------------------------------------------------
__global__ __launch_bounds__(256) void bilinear_mfma(
    const float* __restrict__ h1, const float* __restrict__ t1,
    const uint4* __restrict__ Wfrag, float* __restrict__ part) {
  int n = blockIdx.y;
  int l0 = blockIdx.x * 64;
  int tid = threadIdx.x;
  int wave = tid >> 6, lane = tid & 63;
  int wm = wave & 1, kh = wave >> 1;
  __shared__ __align__(16) uint4 Wl[2][2][896];   // [kh][dbuf][unit]
  __shared__ unsigned short x1s[64][64];

  for (int i = tid; i < 1024; i += 256) {
    int l = i >> 4, bq = (i & 15) * 4;
    float4 v = make_float4(0, 0, 0, 0);
    if (l0 + l < L_) v = *(const float4*)(h1 + (size_t)(l0 + l) * H_ + n * 64 + bq);
    x1s[bq + 0][l] = f2bf(v.x);
    x1s[bq + 1][l] = f2bf(v.y);
    x1s[bq + 2][l] = f2bf(v.z);
    x1s[bq + 3][l] = f2bf(v.w);
  }

  float x2f[2][2][8];
#pragma unroll
  for (int mf = 0; mf < 2; ++mf) {
    int row = l0 + wm * 32 + mf * 16 + (lane & 15);
#pragma unroll
    for (int kc = 0; kc < 2; ++kc) {
      float4 v0 = make_float4(0, 0, 0, 0), v1 = v0;
      if (row < L_) {
        const float* p = t1 + (size_t)row * H_ + n * 64 + kc * 32 + ((lane >> 4) << 3);
        v0 = *(const float4*)p;
        v1 = *(const float4*)(p + 4);
      }
      x2f[mf][kc][0] = v0.x; x2f[mf][kc][1] = v0.y;
      x2f[mf][kc][2] = v0.z; x2f[mf][kc][3] = v0.w;
      x2f[mf][kc][4] = v1.x; x2f[mf][kc][5] = v1.y;
      x2f[mf][kc][6] = v1.z; x2f[mf][kc][7] = v1.w;
    }
  }

  f32x4 acc[2][NF_];
#pragma unroll
  for (int mf = 0; mf < 2; ++mf)
#pragma unroll
    for (int nf = 0; nf < NF_; ++nf)
      acc[mf][nf] = (f32x4){0.f, 0.f, 0.f, 0.f};

  const uint4* gbase = Wfrag + (size_t)n * 64 * 896;
  auto stage = [&](int b, int buf) {
    const uint4* gs = gbase + (size_t)b * 896 + (wm * 7) * 64 + lane;
#pragma unroll
    for (int r = 0; r < 7; ++r)
      gload_lds16(gs + r * 64, &Wl[kh][buf][(wm * 7 + r) * 64]);
  };

  stage(kh * 32, 0);
  __syncthreads();

  for (int s = 0; s < 32; ++s) {
    int b = kh * 32 + s;
    int cur = s & 1, nxt = cur ^ 1;
    if (s + 1 < 32) stage(b + 1, nxt);
    bf16x8 afr[2][2];
#pragma unroll
    for (int mf = 0; mf < 2; ++mf) {
      float x1v = bf2f(x1s[b][wm * 32 + mf * 16 + (lane & 15)]);
#pragma unroll
      for (int kc = 0; kc < 2; ++kc)
#pragma unroll
        for (int j = 0; j < 8; ++j)
          afr[mf][kc][j] = (__bf16)(x1v * x2f[mf][kc][j]);
    }
#pragma unroll
    for (int nf = 0; nf < NF_; ++nf) {
#pragma unroll
      for (int kc = 0; kc < 2; ++kc) {
        bf16x8 bfr = *(const bf16x8*)&Wl[kh][cur][(nf * 2 + kc) * 64 + lane];
#pragma unroll
        for (int mf = 0; mf < 2; ++mf)
          acc[mf][nf] = __builtin_amdgcn_mfma_f32_16x16x32_bf16(
              afr[mf][kc], bfr, acc[mf][nf], 0, 0, 0);
      }
    }
    __syncthreads();
  }

  float* red = (float*)&Wl[0][0][0];
  int rbase = (wm * 64 + lane) * 68;
  if (kh == 1) {
#pragma unroll
    for (int mf = 0; mf < 2; ++mf)
#pragma unroll
      for (int nf = 0; nf < NF_; ++nf)
        *(f32x4*)&red[rbase + (mf * NF_ + nf) * 4] = acc[mf][nf];
  }
  __syncthreads();
  if (kh == 0) {
#pragma unroll
    for (int mf = 0; mf < 2; ++mf)
#pragma unroll
      for (int nf = 0; nf < NF_; ++nf)
        acc[mf][nf] += *(const f32x4*)&red[rbase + (mf * NF_ + nf) * 4];
#pragma unroll
    for (int mf = 0; mf < 2; ++mf) {
#pragma unroll
      for (int nf = 0; nf < NF_; ++nf) {
        int r = nf * 16 + (lane & 15);
        if (r < R_) {
#pragma unroll
          for (int reg = 0; reg < 4; ++reg) {
            int l = l0 + wm * 32 + mf * 16 + ((lane >> 4) << 2) + reg;
            if (l < L_)
              part[((size_t)n * L_ + l) * R_ + r] = acc[mf][nf][reg];
          }
        }
      }
    }
  }
}

// ---------------------------------------------------------------------------
// K6: reduce partials over n, add clsb.
// ---------------------------------------------------------------------------
__global__ void reduce_logits(const float* __restrict__ part, const float* __restrict__ clsb,
                              float* __restrict__ out) {
  int idx = blockIdx.x * 256 + threadIdx.x;
  if (idx < L_ * R_) {
    int r = idx % R_;
    float s = clsb[r];
#pragma unroll
    for (int nn = 0; nn < NB_; ++nn) s += part[(size_t)nn * L_ * R_ + idx];
    out[idx] = s;
  }
}

extern "C" void kernel_launch(void* const* d_in, const int* in_sizes, int n_in,
                              void* d_out, int out_size, void* d_ws, size_t ws_size,
                              hipStream_t stream) {
  const float* hs   = (const float*)d_in[0];
  const float* attn = (const float*)d_in[1];
  const float* mask = (const float*)d_in[2];
  const int*   head = (const int*)d_in[3];
  const int*   tail = (const int*)d_in[4];
  const int*   etyp = (const int*)d_in[5];
  const float* ttab = (const float*)d_in[6];
  const float* dtab = (const float*)d_in[7];
  const float* Wh   = (const float*)d_in[8];
  const float* bh   = (const float*)d_in[9];
  const float* Wt   = (const float*)d_in[10];
  const float* bt   = (const float*)d_in[11];
  const float* clsW = (const float*)d_in[12];
  const float* clsb = (const float*)d_in[13];
  float* out = (float*)d_out;

  float* ws = (float*)d_ws;
  float* ent_att  = ws; ws += (size_t)B_ * E_ * S_;
  float* ent_feat = ws; ws += (size_t)B_ * E_ * H_;
  float* ht_att   = ws; ws += (size_t)L_ * S_;
  float* ht_info  = ws; ws += (size_t)L_ * H_;
  float* h1       = ws; ws += (size_t)L_ * H_;
  float* t1       = ws; ws += (size_t)L_ * H_;
  float* part     = ws; ws += (size_t)NB_ * L_ * R_;
  int* meta = (int*)ws;

  uint4* Wpack_h = (uint4*)ht_att;
  uint4* Wpack_t = (uint4*)part;
  uint4* hsPack  = (uint4*)(part + (size_t)1048576);
  uint4* Wfrag   = (uint4*)ht_att;

  ent_prep<<<B_ * E_, 256, 0, stream>>>(attn, hs, head, tail, ent_att, ent_feat);
  pair_att<<<L_, 256, 0, stream>>>(ent_att, mask, head, tail, etyp, ht_att, meta);
  pack_hs<<<(B_ * KS_HTI * 48 * 64) / 256, 256, 0, stream>>>(hs, hsPack);
  htinfo_mfma<<<dim3(9, 12, B_), 256, 0, stream>>>(ht_att, hsPack, ht_info);
  pack_Wmlp<<<dim3((KS_MLP * 48 * 64) / 256, 2), 256, 0, stream>>>(Wh, Wt, Wpack_h, Wpack_t);
  mlp_mfma<<<dim3(35, 12, 2), 256, 0, stream>>>(ent_feat, ht_info, ttab, dtab, meta,
      Wpack_h, Wpack_t, bh, bt, h1, t1);
  pack_w<<<NB_ * 64, 256, 0, stream>>>(clsW, Wfrag);
  bilinear_mfma<<<dim3(35, NB_), 256, 0, stream>>>(h1, t1, Wfrag, part);
  reduce_logits<<<(L_ * R_ + 255) / 256, 256, 0, stream>>>(part, clsb, out);
}

// Round 6
// 125.807 us; speedup vs baseline: 11.4724x; 1.1281x over previous
//
#include <hip/hip_runtime.h>
#include <hip/hip_bf16.h>
#include <math.h>

#define B_ 4
#define S_ 512
#define H_ 768
#define NH_ 12
#define E_ 24
#define TE_ 20
#define TD_ 20
#define R_ 97
#define DIN_ 1576   // 2*H + TE + TD
#define KPAD_ 1600  // DIN padded to multiple of 32
#define KS_MLP 50   // KPAD/32
#define MF_MLP 140  // 2240/16 m-frags
#define KS_HTI 16   // 512/32
#define P_ 552      // E*(E-1)
#define L_ 2208     // B*P
#define NB_ 12      // H/64
#define NF_ 7       // n-frags of 16 cols covering 97 -> 112

typedef __bf16 bf16x8 __attribute__((ext_vector_type(8)));
typedef float f32x4 __attribute__((ext_vector_type(4)));

__device__ __forceinline__ unsigned short f2bf(float f) {
  union { float f; unsigned u; } c; c.f = f;
  unsigned r = c.u + 0x7FFF + ((c.u >> 16) & 1);
  return (unsigned short)(r >> 16);
}
__device__ __forceinline__ float bf2f(unsigned short b) {
  union { unsigned u; float f; } c; c.u = ((unsigned)b) << 16;
  return c.f;
}
__device__ __forceinline__ unsigned pk2(float a, float b) {
  return (unsigned)f2bf(a) | ((unsigned)f2bf(b) << 16);
}
// async global->LDS, 16B per lane; LDS dest = wave-uniform base + lane*16
__device__ __forceinline__ void gload_lds16(const uint4* g, uint4* l) {
  __builtin_amdgcn_global_load_lds(
      (const __attribute__((address_space(1))) unsigned*)(const void*)g,
      (__attribute__((address_space(3))) unsigned*)(void*)l, 16, 0, 0);
}

// ---------------------------------------------------------------------------
// K1: per-entity gathered attention-row sum over heads + entity features.
// ---------------------------------------------------------------------------
__global__ void ent_prep(const float* __restrict__ attn, const float* __restrict__ hs,
                         const int* __restrict__ head, const int* __restrict__ tail,
                         float* __restrict__ ent_att, float* __restrict__ ent_feat) {
  int be = blockIdx.x;
  int b = be / E_;
  int hd = head[be], tl = tail[be];
  int tid = threadIdx.x;
  const float* abase = attn + (size_t)b * NH_ * S_ * S_;
  for (int s = tid; s < S_; s += 256) {
    float acc = 0.f;
#pragma unroll
    for (int nh = 0; nh < NH_; ++nh) {
      const float* ap = abase + (size_t)nh * S_ * S_;
      acc += ap[(size_t)hd * S_ + s] + ap[(size_t)tl * S_ + s];
    }
    ent_att[(size_t)be * S_ + s] = 0.5f * acc;
  }
  const float* hb = hs + (size_t)b * S_ * H_;
  for (int k = tid; k < H_; k += 256) {
    ent_feat[(size_t)be * H_ + k] = 0.5f * (hb[(size_t)hd * H_ + k] + hb[(size_t)tl * H_ + k]);
  }
}

// ---------------------------------------------------------------------------
// K2: pairwise attention product + mask + normalize; pair metadata.
// ---------------------------------------------------------------------------
__global__ void pair_att(const float* __restrict__ ent_att, const float* __restrict__ mask,
                         const int* __restrict__ head, const int* __restrict__ tail,
                         const int* __restrict__ etype,
                         float* __restrict__ ht_att, int* __restrict__ meta) {
  int l = blockIdx.x;
  int b = l / P_, p = l % P_;
  int i0 = p / (E_ - 1), rem = p % (E_ - 1);
  int i1 = rem + (rem >= i0 ? 1 : 0);
  int tid = threadIdx.x;
  if (tid == 0) {
    meta[0 * L_ + l] = b * E_ + i0;
    meta[1 * L_ + l] = b * E_ + i1;
    meta[2 * L_ + l] = etype[b * E_ + i0];
    meta[3 * L_ + l] = etype[b * E_ + i1];
    int d = abs(tail[b * E_ + i0] - head[b * E_ + i1]);
    int bk = (d >= 2) + (d >= 4) + (d >= 8) + (d >= 16) + (d >= 32) +
             (d >= 64) + (d >= 128) + (d >= 256) + (d >= 512);
    meta[4 * L_ + l] = bk;
  }
  const float* a0 = ent_att + (size_t)(b * E_ + i0) * S_;
  const float* a1 = ent_att + (size_t)(b * E_ + i1) * S_;
  const float* m = mask + (size_t)b * S_;
  float v0 = a0[tid] * a1[tid] * m[tid];
  float v1 = a0[tid + 256] * a1[tid + 256] * m[tid + 256];
  float loc = v0 + v1;
  for (int o = 32; o > 0; o >>= 1) loc += __shfl_down(loc, o, 64);
  __shared__ float red[4];
  if ((tid & 63) == 0) red[tid >> 6] = loc;
  __syncthreads();
  float tot = red[0] + red[1] + red[2] + red[3];
  float inv = 1.f / (tot + 1e-20f);
  ht_att[(size_t)l * S_ + tid] = v0 * inv;
  ht_att[(size_t)l * S_ + tid + 256] = v1 * inv;
}

// ---------------------------------------------------------------------------
// pack_hs: hs (B,S,H f32) -> bf16 fragment-major [b][ks][nt16(48)][lane][8]
// ---------------------------------------------------------------------------
__global__ void pack_hs(const float* __restrict__ hs, uint4* __restrict__ hsP) {
  int u = blockIdx.x * 256 + threadIdx.x;
  if (u >= B_ * KS_HTI * 48 * 64) return;
  int lane = u & 63;
  int t = u >> 6;
  int nt16 = t % 48;
  int t2 = t / 48;
  int ks = t2 % KS_HTI;
  int b = t2 / KS_HTI;
  int n = nt16 * 16 + (lane & 15);
  int k0 = ks * 32 + ((lane >> 4) << 3);
  const float* src = hs + (size_t)b * S_ * H_;
  unsigned w[4];
#pragma unroll
  for (int q = 0; q < 4; ++q) {
    int k = k0 + 2 * q;
    w[q] = pk2(src[(size_t)k * H_ + n], src[(size_t)(k + 1) * H_ + n]);
  }
  uint4 o; o.x = w[0]; o.y = w[1]; o.z = w[2]; o.w = w[3];
  hsP[u] = o;
}

// ---------------------------------------------------------------------------
// pack_Wmlp: Wh/Wt (DIN,H f32) -> bf16 fragment-major [ks][nt16(48)][lane][8]
// ---------------------------------------------------------------------------
__global__ void pack_Wmlp(const float* __restrict__ Wh, const float* __restrict__ Wt,
                          uint4* __restrict__ WpH, uint4* __restrict__ WpT) {
  int u = blockIdx.x * 256 + threadIdx.x;
  if (u >= KS_MLP * 48 * 64) return;
  const float* W = blockIdx.y ? Wt : Wh;
  uint4* Wp = blockIdx.y ? WpT : WpH;
  int lane = u & 63;
  int t = u >> 6;
  int nt16 = t % 48;
  int ks = t / 48;
  int n = nt16 * 16 + (lane & 15);
  int k0 = ks * 32 + ((lane >> 4) << 3);
  unsigned w[4];
#pragma unroll
  for (int q = 0; q < 4; ++q) {
    int k = k0 + 2 * q;
    float v0 = (k < DIN_) ? W[(size_t)k * H_ + n] : 0.f;
    float v1 = (k + 1 < DIN_) ? W[(size_t)(k + 1) * H_ + n] : 0.f;
    w[q] = pk2(v0, v1);
  }
  uint4 o; o.x = w[0]; o.y = w[1]; o.z = w[2]; o.w = w[3];
  Wp[u] = o;
}

// ---------------------------------------------------------------------------
// pack_allx: build gathered A matrices (all_h / all_t) in bf16 frag-major
// [mf(140)][ks(50)][lane][8]: row = mf*16+(lane&15), k = ks*32+(lane>>4)*8+j.
// One thread per (unit,lane). Hoists the gather + f32->bf16 cvt out of mlp.
// ---------------------------------------------------------------------------
__global__ void pack_allx(const float* __restrict__ ent_feat, const float* __restrict__ ht_info,
                          const float* __restrict__ ttab, const float* __restrict__ dtab,
                          const int* __restrict__ meta,
                          uint4* __restrict__ axH, uint4* __restrict__ axT) {
  int idx = blockIdx.x * 256 + threadIdx.x;   // 2*7000*64 = 896000 exact
  int lane = idx & 63;
  int unit = idx >> 6;
  int half = unit / (MF_MLP * KS_MLP);
  int rem = unit % (MF_MLP * KS_MLP);
  int mf = rem / KS_MLP, ks = rem % KS_MLP;
  int row = mf * 16 + (lane & 15);
  int k = ks * 32 + ((lane >> 4) << 3);
  uint4 d; d.x = d.y = d.z = d.w = 0;
  if (row < L_) {
    int frow = meta[half * L_ + row];
    int trow = meta[(2 + half) * L_ + row];
    int db = meta[4 * L_ + row];
    if (k < 768) {
      const float* p = ent_feat + (size_t)frow * H_ + k;
      float4 v0 = *(const float4*)p, v1 = *(const float4*)(p + 4);
      d.x = pk2(v0.x, v0.y); d.y = pk2(v0.z, v0.w);
      d.z = pk2(v1.x, v1.y); d.w = pk2(v1.z, v1.w);
    } else if (k < 1536) {
      const float* p = ht_info + (size_t)row * H_ + (k - 768);
      float4 v0 = *(const float4*)p, v1 = *(const float4*)(p + 4);
      d.x = pk2(v0.x, v0.y); d.y = pk2(v0.z, v0.w);
      d.z = pk2(v1.x, v1.y); d.w = pk2(v1.z, v1.w);
    } else {
      float v[8];
#pragma unroll
      for (int j = 0; j < 8; ++j) {
        int e = k + j;
        v[j] = (e < 1556) ? ttab[trow * TE_ + (e - 1536)]
             : (e < 1576) ? dtab[db * TD_ + (e - 1556)] : 0.f;
      }
      d.x = pk2(v[0], v[1]); d.y = pk2(v[2], v[3]);
      d.z = pk2(v[4], v[5]); d.w = pk2(v[6], v[7]);
    }
  }
  (half ? axT : axH)[(size_t)rem * 64 + lane] = d;
}

// ---------------------------------------------------------------------------
// htinfo_mfma v3: BM=64 BN=64 BK=64, 8 K-steps, 4 waves (2m x 2n).
// B via global_load_lds (2 chunks/wave/step); A gathered f32->bf16 (contiguous
// rows), 2 chunks/thread, ds_write after compute. Grid (9,12,4)=432.
// ---------------------------------------------------------------------------
__global__ __launch_bounds__(256) void htinfo_mfma(
    const float* __restrict__ htatt, const uint4* __restrict__ hsP,
    float* __restrict__ htinfo) {
  int b = blockIdx.z;
  int m0 = blockIdx.x * 64;
  int nt0 = blockIdx.y * 4;
  int tid = threadIdx.x;
  int wave = tid >> 6, lane = tid & 63;
  int wm = wave & 1, wn = wave >> 1;
  __shared__ __align__(16) uint4 Ash[2][512];
  __shared__ __align__(16) uint4 Bsh[2][512];

  f32x4 acc[2][2];
#pragma unroll
  for (int i = 0; i < 2; ++i)
#pragma unroll
    for (int j = 0; j < 2; ++j) acc[i][j] = (f32x4){0.f, 0.f, 0.f, 0.f};

  auto stageB = [&](int s, int buf) {
#pragma unroll
    for (int i = 0; i < 2; ++i) {
      int c = wave * 2 + i;
      int ntl = c >> 1, kslot = c & 1;
      gload_lds16(hsP + ((size_t)(b * KS_HTI + s * 2 + kslot) * 48 + nt0 + ntl) * 64 + lane,
                  &Bsh[buf][c * 64]);
    }
  };
  auto gatherA = [&](int s, int c, uint4& d) {
    int mfl = c >> 1, kslot = c & 1;
    int row = m0 + mfl * 16 + (lane & 15);
    if (row >= P_) { d.x = d.y = d.z = d.w = 0; return; }
    int k = s * 64 + kslot * 32 + ((lane >> 4) << 3);
    const float* p = htatt + ((size_t)b * P_ + row) * S_ + k;
    float4 v0 = *(const float4*)p, v1 = *(const float4*)(p + 4);
    d.x = pk2(v0.x, v0.y); d.y = pk2(v0.z, v0.w);
    d.z = pk2(v1.x, v1.y); d.w = pk2(v1.z, v1.w);
  };

  {
    uint4 a0_, a1_;
    gatherA(0, wave, a0_); gatherA(0, wave + 4, a1_);
    Ash[0][wave * 64 + lane] = a0_;
    Ash[0][(wave + 4) * 64 + lane] = a1_;
    stageB(0, 0);
  }
  __syncthreads();

  for (int s = 0; s < 8; ++s) {
    int cur = s & 1, nxt = cur ^ 1;
    bool more = (s + 1 < 8);
    uint4 aN0, aN1;
    if (more) {
      stageB(s + 1, nxt);
      gatherA(s + 1, wave, aN0); gatherA(s + 1, wave + 4, aN1);
    }
    bf16x8 af[2][2], bf[2][2];
#pragma unroll
    for (int mf = 0; mf < 2; ++mf)
#pragma unroll
      for (int kc = 0; kc < 2; ++kc)
        af[mf][kc] = *(const bf16x8*)&Ash[cur][((wm * 2 + mf) * 2 + kc) * 64 + lane];
#pragma unroll
    for (int nf = 0; nf < 2; ++nf)
#pragma unroll
      for (int kc = 0; kc < 2; ++kc)
        bf[nf][kc] = *(const bf16x8*)&Bsh[cur][((wn * 2 + nf) * 2 + kc) * 64 + lane];
#pragma unroll
    for (int kc = 0; kc < 2; ++kc)
#pragma unroll
      for (int nf = 0; nf < 2; ++nf)
#pragma unroll
        for (int mf = 0; mf < 2; ++mf)
          acc[mf][nf] = __builtin_amdgcn_mfma_f32_16x16x32_bf16(af[mf][kc], bf[nf][kc], acc[mf][nf], 0, 0, 0);
    if (more) {
      Ash[nxt][wave * 64 + lane] = aN0;
      Ash[nxt][(wave + 4) * 64 + lane] = aN1;
    }
    __syncthreads();
  }

#pragma unroll
  for (int mf = 0; mf < 2; ++mf)
#pragma unroll
    for (int nf = 0; nf < 2; ++nf) {
      int n = nt0 * 16 + (wn * 2 + nf) * 16 + (lane & 15);
#pragma unroll
      for (int reg = 0; reg < 4; ++reg) {
        int l = m0 + (wm * 2 + mf) * 16 + ((lane >> 4) << 2) + reg;
        if (l < P_)
          htinfo[((size_t)b * P_ + l) * H_ + n] = acc[mf][nf][reg];
      }
    }
}

// ---------------------------------------------------------------------------
// mlp_mfma v3: pure GEMM. BM=64 BN=64 BK=64, 25 K-steps, 4 waves (2m x 2n),
// A and B both frag-major packed, staged via global_load_lds (4/wave/step).
// 8 MFMA per wave per step. Grid (35,12,2)=840, LDS 32KB.
// ---------------------------------------------------------------------------
__global__ __launch_bounds__(256) void mlp_mfma(
    const uint4* __restrict__ Apk_h, const uint4* __restrict__ Apk_t,
    const uint4* __restrict__ Wp_h, const uint4* __restrict__ Wp_t,
    const float* __restrict__ bh, const float* __restrict__ bt,
    float* __restrict__ h1, float* __restrict__ t1) {
  int half = blockIdx.z;
  const uint4* Apk = half ? Apk_t : Apk_h;
  const uint4* Wp = half ? Wp_t : Wp_h;
  const float* bias = half ? bt : bh;
  float* out = half ? t1 : h1;
  int mf0 = blockIdx.x * 4;
  int nt0 = blockIdx.y * 4;
  int tid = threadIdx.x;
  int wave = tid >> 6, lane = tid & 63;
  int wm = wave & 1, wn = wave >> 1;
  __shared__ __align__(16) uint4 Ash[2][512];
  __shared__ __align__(16) uint4 Bsh[2][512];

  f32x4 acc[2][2];
#pragma unroll
  for (int i = 0; i < 2; ++i)
#pragma unroll
    for (int j = 0; j < 2; ++j) acc[i][j] = (f32x4){0.f, 0.f, 0.f, 0.f};

  auto stage = [&](int s, int buf) {
#pragma unroll
    for (int i = 0; i < 2; ++i) {
      int c = wave * 2 + i;
      int cl = c >> 1, kslot = c & 1;
      gload_lds16(Apk + ((size_t)(mf0 + cl) * KS_MLP + s * 2 + kslot) * 64 + lane,
                  &Ash[buf][c * 64]);
      gload_lds16(Wp + ((size_t)(s * 2 + kslot) * 48 + nt0 + cl) * 64 + lane,
                  &Bsh[buf][c * 64]);
    }
  };

  stage(0, 0);
  __syncthreads();

  for (int s = 0; s < 25; ++s) {
    int cur = s & 1, nxt = cur ^ 1;
    if (s + 1 < 25) stage(s + 1, nxt);
    bf16x8 af[2][2], bf[2][2];
#pragma unroll
    for (int mf = 0; mf < 2; ++mf)
#pragma unroll
      for (int kc = 0; kc < 2; ++kc)
        af[mf][kc] = *(const bf16x8*)&Ash[cur][((wm * 2 + mf) * 2 + kc) * 64 + lane];
#pragma unroll
    for (int nf = 0; nf < 2; ++nf)
#pragma unroll
      for (int kc = 0; kc < 2; ++kc)
        bf[nf][kc] = *(const bf16x8*)&Bsh[cur][((wn * 2 + nf) * 2 + kc) * 64 + lane];
#pragma unroll
    for (int kc = 0; kc < 2; ++kc)
#pragma unroll
      for (int nf = 0; nf < 2; ++nf)
#pragma unroll
        for (int mf = 0; mf < 2; ++mf)
          acc[mf][nf] = __builtin_amdgcn_mfma_f32_16x16x32_bf16(af[mf][kc], bf[nf][kc], acc[mf][nf], 0, 0, 0);
    __syncthreads();
  }

#pragma unroll
  for (int mf = 0; mf < 2; ++mf)
#pragma unroll
    for (int nf = 0; nf < 2; ++nf) {
      int n = nt0 * 16 + (wn * 2 + nf) * 16 + (lane & 15);
      float bv = bias[n];
#pragma unroll
      for (int reg = 0; reg < 4; ++reg) {
        int l = (mf0 + wm * 2 + mf) * 16 + ((lane >> 4) << 2) + reg;
        if (l < L_)
          out[(size_t)l * H_ + n] = tanhf(acc[mf][nf][reg] + bv);
      }
    }
}

// ---------------------------------------------------------------------------
// K5a: pre-pack clsW -> fragment-major bf16 for the bilinear B-operand.
// ---------------------------------------------------------------------------
__global__ void pack_w(const float* __restrict__ clsW, uint4* __restrict__ Wfrag) {
  int nb = blockIdx.x;            // n*64 + b
  __shared__ float Wls[64][98];
  int tid = threadIdx.x;
  const float* src = clsW + (size_t)nb * 64 * R_;
  for (int idx = tid; idx < 64 * R_; idx += 256) {
    Wls[idx / R_][idx % R_] = src[idx];
  }
  __syncthreads();
  for (int u = tid; u < 896; u += 256) {
    int nf = u >> 7;
    int kc = (u >> 6) & 1;
    int lane = u & 63;
    int r = (lane & 15) + 16 * nf;
    unsigned w[4];
#pragma unroll
    for (int q = 0; q < 4; ++q) {
      int c0 = ((lane >> 4) << 3) + 2 * q + 32 * kc;
      float v0 = (r < R_) ? Wls[c0][r] : 0.f;
      float v1 = (r < R_) ? Wls[c0 + 1][r] : 0.f;
      w[q] = (unsigned)f2bf(v0) | ((unsigned)f2bf(v1) << 16);
    }
    uint4 o; o.x = w[0]; o.y = w[1]; o.z = w[2]; o.w = w[3];
    Wfrag[(size_t)nb * 896 + u] = o;
  }
}

// ---------------------------------------------------------------------------
// K5b: bilinear MFMA (as R5: 4 waves, wave-pair K-split, gload_lds W).
// ---------------------------------------------------------------------------
__global__ __launch_bounds__(256) void bilinear_mfma(
    const float* __restrict__ h1, const float* __restrict__ t1,
    const uint4* __restrict__ Wfrag, float* __restrict__ part) {
  int n = blockIdx.y;
  int l0 = blockIdx.x * 64;
  int tid = threadIdx.x;
  int wave = tid >> 6, lane = tid & 63;
  int wm = wave & 1, kh = wave >> 1;
  __shared__ __align__(16) uint4 Wl[2][2][896];   // [kh][dbuf][unit]
  __shared__ unsigned short x1s[64][64];

  for (int i = tid; i < 1024; i += 256) {
    int l = i >> 4, bq = (i & 15) * 4;
    float4 v = make_float4(0, 0, 0, 0);
    if (l0 + l < L_) v = *(const float4*)(h1 + (size_t)(l0 + l) * H_ + n * 64 + bq);
    x1s[bq + 0][l] = f2bf(v.x);
    x1s[bq + 1][l] = f2bf(v.y);
    x1s[bq + 2][l] = f2bf(v.z);
    x1s[bq + 3][l] = f2bf(v.w);
  }

  float x2f[2][2][8];
#pragma unroll
  for (int mf = 0; mf < 2; ++mf) {
    int row = l0 + wm * 32 + mf * 16 + (lane & 15);
#pragma unroll
    for (int kc = 0; kc < 2; ++kc) {
      float4 v0 = make_float4(0, 0, 0, 0), v1 = v0;
      if (row < L_) {
        const float* p = t1 + (size_t)row * H_ + n * 64 + kc * 32 + ((lane >> 4) << 3);
        v0 = *(const float4*)p;
        v1 = *(const float4*)(p + 4);
      }
      x2f[mf][kc][0] = v0.x; x2f[mf][kc][1] = v0.y;
      x2f[mf][kc][2] = v0.z; x2f[mf][kc][3] = v0.w;
      x2f[mf][kc][4] = v1.x; x2f[mf][kc][5] = v1.y;
      x2f[mf][kc][6] = v1.z; x2f[mf][kc][7] = v1.w;
    }
  }

  f32x4 acc[2][NF_];
#pragma unroll
  for (int mf = 0; mf < 2; ++mf)
#pragma unroll
    for (int nf = 0; nf < NF_; ++nf)
      acc[mf][nf] = (f32x4){0.f, 0.f, 0.f, 0.f};

  const uint4* gbase = Wfrag + (size_t)n * 64 * 896;
  auto stage = [&](int b, int buf) {
    const uint4* gs = gbase + (size_t)b * 896 + (wm * 7) * 64 + lane;
#pragma unroll
    for (int r = 0; r < 7; ++r)
      gload_lds16(gs + r * 64, &Wl[kh][buf][(wm * 7 + r) * 64]);
  };

  stage(kh * 32, 0);
  __syncthreads();

  for (int s = 0; s < 32; ++s) {
    int b = kh * 32 + s;
    int cur = s & 1, nxt = cur ^ 1;
    if (s + 1 < 32) stage(b + 1, nxt);
    bf16x8 afr[2][2];
#pragma unroll
    for (int mf = 0; mf < 2; ++mf) {
      float x1v = bf2f(x1s[b][wm * 32 + mf * 16 + (lane & 15)]);
#pragma unroll
      for (int kc = 0; kc < 2; ++kc)
#pragma unroll
        for (int j = 0; j < 8; ++j)
          afr[mf][kc][j] = (__bf16)(x1v * x2f[mf][kc][j]);
    }
#pragma unroll
    for (int nf = 0; nf < NF_; ++nf) {
#pragma unroll
      for (int kc = 0; kc < 2; ++kc) {
        bf16x8 bfr = *(const bf16x8*)&Wl[kh][cur][(nf * 2 + kc) * 64 + lane];
#pragma unroll
        for (int mf = 0; mf < 2; ++mf)
          acc[mf][nf] = __builtin_amdgcn_mfma_f32_16x16x32_bf16(
              afr[mf][kc], bfr, acc[mf][nf], 0, 0, 0);
      }
    }
    __syncthreads();
  }

  float* red = (float*)&Wl[0][0][0];
  int rbase = (wm * 64 + lane) * 68;
  if (kh == 1) {
#pragma unroll
    for (int mf = 0; mf < 2; ++mf)
#pragma unroll
      for (int nf = 0; nf < NF_; ++nf)
        *(f32x4*)&red[rbase + (mf * NF_ + nf) * 4] = acc[mf][nf];
  }
  __syncthreads();
  if (kh == 0) {
#pragma unroll
    for (int mf = 0; mf < 2; ++mf)
#pragma unroll
      for (int nf = 0; nf < NF_; ++nf)
        acc[mf][nf] += *(const f32x4*)&red[rbase + (mf * NF_ + nf) * 4];
#pragma unroll
    for (int mf = 0; mf < 2; ++mf) {
#pragma unroll
      for (int nf = 0; nf < NF_; ++nf) {
        int r = nf * 16 + (lane & 15);
        if (r < R_) {
#pragma unroll
          for (int reg = 0; reg < 4; ++reg) {
            int l = l0 + wm * 32 + mf * 16 + ((lane >> 4) << 2) + reg;
            if (l < L_)
              part[((size_t)n * L_ + l) * R_ + r] = acc[mf][nf][reg];
          }
        }
      }
    }
  }
}

// ---------------------------------------------------------------------------
// K6: reduce partials over n, add clsb.
// ---------------------------------------------------------------------------
__global__ void reduce_logits(const float* __restrict__ part, const float* __restrict__ clsb,
                              float* __restrict__ out) {
  int idx = blockIdx.x * 256 + threadIdx.x;
  if (idx < L_ * R_) {
    int r = idx % R_;
    float s = clsb[r];
#pragma unroll
    for (int nn = 0; nn < NB_; ++nn) s += part[(size_t)nn * L_ * R_ + idx];
    out[idx] = s;
  }
}

extern "C" void kernel_launch(void* const* d_in, const int* in_sizes, int n_in,
                              void* d_out, int out_size, void* d_ws, size_t ws_size,
                              hipStream_t stream) {
  const float* hs   = (const float*)d_in[0];
  const float* attn = (const float*)d_in[1];
  const float* mask = (const float*)d_in[2];
  const int*   head = (const int*)d_in[3];
  const int*   tail = (const int*)d_in[4];
  const int*   etyp = (const int*)d_in[5];
  const float* ttab = (const float*)d_in[6];
  const float* dtab = (const float*)d_in[7];
  const float* Wh   = (const float*)d_in[8];
  const float* bh   = (const float*)d_in[9];
  const float* Wt   = (const float*)d_in[10];
  const float* bt   = (const float*)d_in[11];
  const float* clsW = (const float*)d_in[12];
  const float* clsb = (const float*)d_in[13];
  float* out = (float*)d_out;

  // Clean (non-aliased) workspace layout, ~69 MB.
  float* ws = (float*)d_ws;
  float* ent_att  = ws; ws += (size_t)B_ * E_ * S_;        // 49152
  float* ent_feat = ws; ws += (size_t)B_ * E_ * H_;        // 73728
  float* ht_att   = ws; ws += (size_t)L_ * S_;             // 1130496
  float* ht_info  = ws; ws += (size_t)L_ * H_;             // 1695744
  float* h1       = ws; ws += (size_t)L_ * H_;             // 1695744
  float* t1       = ws; ws += (size_t)L_ * H_;             // 1695744
  float* part     = ws; ws += (size_t)NB_ * L_ * R_;       // 2570112
  uint4* Wpack_h  = (uint4*)ws; ws += (size_t)KS_MLP * 48 * 64 * 4;   // 589824 f
  uint4* Wpack_t  = (uint4*)ws; ws += (size_t)KS_MLP * 48 * 64 * 4;
  uint4* hsPack   = (uint4*)ws; ws += (size_t)B_ * KS_HTI * 48 * 64 * 4; // 786432 f
  uint4* Wfrag    = (uint4*)ws; ws += (size_t)NB_ * 64 * 896 * 4;     // 2752512 f
  uint4* allx_h   = (uint4*)ws; ws += (size_t)MF_MLP * KS_MLP * 64 * 4; // 1792000 f
  uint4* allx_t   = (uint4*)ws; ws += (size_t)MF_MLP * KS_MLP * 64 * 4;
  int* meta = (int*)ws;                                    // 5*L ints

  ent_prep<<<B_ * E_, 256, 0, stream>>>(attn, hs, head, tail, ent_att, ent_feat);
  pair_att<<<L_, 256, 0, stream>>>(ent_att, mask, head, tail, etyp, ht_att, meta);
  pack_hs<<<(B_ * KS_HTI * 48 * 64) / 256, 256, 0, stream>>>(hs, hsPack);
  htinfo_mfma<<<dim3(9, 12, B_), 256, 0, stream>>>(ht_att, hsPack, ht_info);
  pack_Wmlp<<<dim3((KS_MLP * 48 * 64) / 256, 2), 256, 0, stream>>>(Wh, Wt, Wpack_h, Wpack_t);
  pack_allx<<<(2 * MF_MLP * KS_MLP * 64) / 256, 256, 0, stream>>>(
      ent_feat, ht_info, ttab, dtab, meta, allx_h, allx_t);
  mlp_mfma<<<dim3(35, 12, 2), 256, 0, stream>>>(allx_h, allx_t,
      Wpack_h, Wpack_t, bh, bt, h1, t1);
  pack_w<<<NB_ * 64, 256, 0, stream>>>(clsW, Wfrag);
  bilinear_mfma<<<dim3(35, NB_), 256, 0, stream>>>(h1, t1, Wfrag, part);
  reduce_logits<<<(L_ * R_ + 255) / 256, 256, 0, stream>>>(part, clsb, out);
}